// Round 14
// baseline (464.588 us; speedup 1.0000x reference)
//
#include <hip/hip_runtime.h>
#include <cstdint>
#include <cstddef>

#define NN 8192
#define KFIN 1024
#define KFOUT 256
#define MAXD 192
#define LRALPHA 0.2f

typedef float f32x4 __attribute__((ext_vector_type(4)));

// ---------------------------------------------------------------------------
// Kernel A: dense adj -> CSR neighbor lists (stable ascending-column order via
// 4x ballot on float4 nontemporal loads), degree, s2 = off-diagonal degree.
// ---------------------------------------------------------------------------
__global__ void __launch_bounds__(256) k_build_csr(
    const float* __restrict__ adj, int* __restrict__ nbr,
    int* __restrict__ deg, int* __restrict__ s2v) {
  const int wave = threadIdx.x >> 6;
  const int lane = threadIdx.x & 63;
  const int row = blockIdx.x * 4 + wave;
  const float* arow = adj + (size_t)row * NN;
  int* outp = nbr + (size_t)row * MAXD;
  int count = 0;
  int dflag = 0;
  const unsigned long long below = (1ull << lane) - 1ull;
  for (int c0 = 0; c0 < NN; c0 += 256) {
    const int c = c0 + lane * 4;
    const f32x4 v = __builtin_nontemporal_load(
        reinterpret_cast<const f32x4*>(arow + c));
    const unsigned long long m0 = __ballot(v[0] > 0.0f);
    const unsigned long long m1 = __ballot(v[1] > 0.0f);
    const unsigned long long m2 = __ballot(v[2] > 0.0f);
    const unsigned long long m3 = __ballot(v[3] > 0.0f);
    int pos = count + (int)(__popcll(m0 & below) + __popcll(m1 & below) +
                            __popcll(m2 & below) + __popcll(m3 & below));
    if (v[0] > 0.0f) { if (pos < MAXD) outp[pos] = c + 0; ++pos; if (c + 0 == row) dflag = 1; }
    if (v[1] > 0.0f) { if (pos < MAXD) outp[pos] = c + 1; ++pos; if (c + 1 == row) dflag = 1; }
    if (v[2] > 0.0f) { if (pos < MAXD) outp[pos] = c + 2; ++pos; if (c + 2 == row) dflag = 1; }
    if (v[3] > 0.0f) { if (pos < MAXD) outp[pos] = c + 3; ++pos; if (c + 3 == row) dflag = 1; }
    count += (int)(__popcll(m0) + __popcll(m1) + __popcll(m2) + __popcll(m3));
  }
  const int anyd = __any(dflag) ? 1 : 0;
  if (lane == 0) {
    deg[row] = count < MAXD ? count : MAXD;
    s2v[row] = count - anyd;
  }
}

// ---------------------------------------------------------------------------
// Kernel B: Wh = h @ W, f32 tiled GEMM (64x64 tile, 4x4 per thread, BK=32).
// ---------------------------------------------------------------------------
__global__ void __launch_bounds__(256) k_gemm(
    const float* __restrict__ A, const float* __restrict__ B,
    float* __restrict__ C) {
  __shared__ float As[32][65];
  __shared__ float Bs[32][65];
  const int tid = threadIdx.x;
  const int brow = blockIdx.y * 64;
  const int bcol = blockIdx.x * 64;
  const int tx = tid & 15;
  const int ty = tid >> 4;
  float acc[4][4];
#pragma unroll
  for (int i = 0; i < 4; ++i)
#pragma unroll
    for (int j = 0; j < 4; ++j) acc[i][j] = 0.0f;
  const int ar = tid >> 2;
  const int ac = (tid & 3) << 2;
  const int br = tid >> 4;
  const int bc = (tid & 15) << 2;
  for (int k0 = 0; k0 < KFIN; k0 += 32) {
    const float4 av0 =
        *reinterpret_cast<const float4*>(A + (size_t)(brow + ar) * KFIN + k0 + ac);
    const float4 av1 =
        *reinterpret_cast<const float4*>(A + (size_t)(brow + ar) * KFIN + k0 + 16 + ac);
    const float4 bv0 =
        *reinterpret_cast<const float4*>(B + (size_t)(k0 + br) * KFOUT + bcol + bc);
    const float4 bv1 =
        *reinterpret_cast<const float4*>(B + (size_t)(k0 + 16 + br) * KFOUT + bcol + bc);
    As[ac + 0][ar] = av0.x;
    As[ac + 1][ar] = av0.y;
    As[ac + 2][ar] = av0.z;
    As[ac + 3][ar] = av0.w;
    As[16 + ac + 0][ar] = av1.x;
    As[16 + ac + 1][ar] = av1.y;
    As[16 + ac + 2][ar] = av1.z;
    As[16 + ac + 3][ar] = av1.w;
    Bs[br][bc + 0] = bv0.x;
    Bs[br][bc + 1] = bv0.y;
    Bs[br][bc + 2] = bv0.z;
    Bs[br][bc + 3] = bv0.w;
    Bs[16 + br][bc + 0] = bv1.x;
    Bs[16 + br][bc + 1] = bv1.y;
    Bs[16 + br][bc + 2] = bv1.z;
    Bs[16 + br][bc + 3] = bv1.w;
    __syncthreads();
#pragma unroll
    for (int kk = 0; kk < 32; ++kk) {
      const float a0 = As[kk][ty * 4 + 0];
      const float a1 = As[kk][ty * 4 + 1];
      const float a2 = As[kk][ty * 4 + 2];
      const float a3 = As[kk][ty * 4 + 3];
      const float b0 = Bs[kk][tx * 4 + 0];
      const float b1 = Bs[kk][tx * 4 + 1];
      const float b2 = Bs[kk][tx * 4 + 2];
      const float b3 = Bs[kk][tx * 4 + 3];
      acc[0][0] += a0 * b0; acc[0][1] += a0 * b1; acc[0][2] += a0 * b2; acc[0][3] += a0 * b3;
      acc[1][0] += a1 * b0; acc[1][1] += a1 * b1; acc[1][2] += a1 * b2; acc[1][3] += a1 * b3;
      acc[2][0] += a2 * b0; acc[2][1] += a2 * b1; acc[2][2] += a2 * b2; acc[2][3] += a2 * b3;
      acc[3][0] += a3 * b0; acc[3][1] += a3 * b1; acc[3][2] += a3 * b2; acc[3][3] += a3 * b3;
    }
    __syncthreads();
  }
#pragma unroll
  for (int i = 0; i < 4; ++i) {
#pragma unroll
    for (int j = 0; j < 4; ++j) {
      C[(size_t)(brow + ty * 4 + i) * KFOUT + bcol + tx * 4 + j] = acc[i][j];
    }
  }
}

// ---------------------------------------------------------------------------
// Kernel C: Wh1/Wh2 row dots, one wave per row (shuffle reduce, no barriers).
// ---------------------------------------------------------------------------
__global__ void __launch_bounds__(256) k_rowdots(
    const float* __restrict__ Wh, const float* __restrict__ a,
    float* __restrict__ Wh1, float* __restrict__ Wh2) {
  const int wave = threadIdx.x >> 6;
  const int lane = threadIdx.x & 63;
  const int row = blockIdx.x * 4 + wave;
  const float4 w = *reinterpret_cast<const float4*>(Wh + (size_t)row * KFOUT + lane * 4);
  const float4 aA = *reinterpret_cast<const float4*>(a + lane * 4);
  const float4 aB = *reinterpret_cast<const float4*>(a + KFOUT + lane * 4);
  float sA = w.x * aA.x + w.y * aA.y + w.z * aA.z + w.w * aA.w;
  float sB = w.x * aB.x + w.y * aB.y + w.z * aB.z + w.w * aB.w;
  for (int o = 32; o > 0; o >>= 1) {
    sA += __shfl_xor(sA, o);
    sB += __shfl_xor(sB, o);
  }
  if (lane == 0) {
    Wh1[row] = sA;
    Wh2[row] = sB;
  }
}

// ---------------------------------------------------------------------------
// Kernel D1: per-row softmax stats (m, Z) + row-normalized attention values
// + octant split counts qb8 + packed mz=(m, 1/Z) -- one edge gather.
// ---------------------------------------------------------------------------
__global__ void __launch_bounds__(256) k_stats(
    const int* __restrict__ nbr, const int* __restrict__ deg,
    const float* __restrict__ Wh1, const float* __restrict__ Wh2,
    float2* __restrict__ mz, float* __restrict__ att,
    short* __restrict__ qb8) {
  const int wave = threadIdx.x >> 6;
  const int lane = threadIdx.x & 63;
  const int row = blockIdx.x * 4 + wave;
  const int d = deg[row];
  const size_t rowbase = (size_t)row * MAXD;
  const int* cols = nbr + rowbase;
  const float w1 = Wh1[row];
  int c0 = 0x7fffffff, c1 = 0x7fffffff, c2 = 0x7fffffff;
  float e0 = -1e30f, e1 = -1e30f, e2 = -1e30f;
  const bool a0 = lane < d, a1 = lane + 64 < d, a2 = lane + 128 < d;
  if (a0) { c0 = cols[lane];       float x = w1 + Wh2[c0]; e0 = x > 0.0f ? x : LRALPHA * x; }
  if (a1) { c1 = cols[lane + 64];  float x = w1 + Wh2[c1]; e1 = x > 0.0f ? x : LRALPHA * x; }
  if (a2) { c2 = cols[lane + 128]; float x = w1 + Wh2[c2]; e2 = x > 0.0f ? x : LRALPHA * x; }
  float mx = fmaxf(e0, fmaxf(e1, e2));
  for (int o = 32; o > 0; o >>= 1) mx = fmaxf(mx, __shfl_xor(mx, o));
  const float x0 = a0 ? expf(e0 - mx) : 0.0f;
  const float x1 = a1 ? expf(e1 - mx) : 0.0f;
  const float x2 = a2 ? expf(e2 - mx) : 0.0f;
  float sum = x0 + x1 + x2;
  for (int o = 32; o > 0; o >>= 1) sum += __shfl_xor(sum, o);
  const float Z = (d > 0) ? sum : 1.0f;
  const float invZ = 1.0f / Z;
  if (a0) att[rowbase + lane] = x0 * invZ;
  if (a1) att[rowbase + lane + 64] = x1 * invZ;
  if (a2) att[rowbase + lane + 128] = x2 * invZ;
  int b[7] = {0, 0, 0, 0, 0, 0, 0};
#pragma unroll
  for (int m = 1; m <= 7; ++m) {
    b[m - 1] = (int)__popcll(__ballot(a0 && c0 < m * 1024)) +
               (int)__popcll(__ballot(a1 && c1 < m * 1024)) +
               (int)__popcll(__ballot(a2 && c2 < m * 1024));
  }
  if (lane == 0) {
    mz[row] = make_float2(mx, invZ);
    short* q = qb8 + (size_t)row * 8;
    q[0] = (short)b[0]; q[1] = (short)b[1]; q[2] = (short)b[2]; q[3] = (short)b[3];
    q[4] = (short)b[4]; q[5] = (short)b[5]; q[6] = (short)b[6]; q[7] = (short)d;
  }
}

// ---------------------------------------------------------------------------
// Kernel D2: packed transpose-edge values (uses packed mz: 2 gathers + mul).
// ---------------------------------------------------------------------------
__global__ void __launch_bounds__(256) k_att(
    const int* __restrict__ nbr, const int* __restrict__ deg,
    const float* __restrict__ Wh1, const float* __restrict__ Wh2,
    const float2* __restrict__ mz, int2* __restrict__ edgesT) {
  const int wave = threadIdx.x >> 6;
  const int lane = threadIdx.x & 63;
  const int row = blockIdx.x * 4 + wave;
  const int d = deg[row];
  const size_t rowbase = (size_t)row * MAXD;
  const int* cols = nbr + rowbase;
  const float w2r = Wh2[row];
  for (int t = lane; t < d; t += 64) {
    const int j = cols[t];
    float e2 = Wh1[j] + w2r;
    e2 = e2 > 0.0f ? e2 : LRALPHA * e2;
    const float2 m = mz[j];
    const float v = expf(e2 - m.x) * m.y;
    edgesT[rowbase + t] = make_int2(j, __float_as_int(v));
  }
}

// ---------------------------------------------------------------------------
// Kernel E: per row i, 512 threads (8 waves). FUSED: two-step prune + h_prime.
// h_prime gather moved to the END (after the out1 nt-store loop): its
// scattered Wh reads overlap the store drain instead of competing with the
// scatter phase's edgesT loads (R13 showed ~15us interference up front).
// wvals/kcols stay live in LDS through the select; sqb (dead after scatter)
// parks the partials. Same dot order per (row,c) -> bitwise-identical out0.
// ---------------------------------------------------------------------------
__global__ void __launch_bounds__(512) k_twostep(
    const int* __restrict__ nbr, const int* __restrict__ deg,
    const int* __restrict__ s2v, const float* __restrict__ att,
    const int2* __restrict__ edgesT, const short* __restrict__ qb8,
    const float* __restrict__ Wh, float* __restrict__ out1,
    float* __restrict__ out0) {
  __shared__ float comb[NN];                 // 32768 B
  __shared__ float wvals[MAXD];              //   768 B
  __shared__ unsigned short kcols[MAXD];     //   384 B
  __shared__ short sqb[MAXD][8];             //  3072 B (reused as hp[512])
  __shared__ unsigned int hist[256];         //  1024 B
  __shared__ unsigned int scomp[512];        //  2048 B
  __shared__ unsigned int shPrefix;
  __shared__ int shRemaining;
  __shared__ int shNc;
  const int tid = threadIdx.x;
  const int wave = tid >> 6;
  const int lane = tid & 63;
  const int row = blockIdx.x;
  const f32x4 z4 = {0.0f, 0.0f, 0.0f, 0.0f};
  for (int j = tid * 4; j < NN; j += 2048)
    *reinterpret_cast<f32x4*>(&comb[j]) = z4;
  const int d = deg[row];
  const int* cols = nbr + (size_t)row * MAXD;
  const float* arow = att + (size_t)row * MAXD;
  for (int t = tid; t < d; t += 512) {
    const int c = cols[t];
    kcols[t] = (unsigned short)c;
    wvals[t] = arow[t];
    *reinterpret_cast<int4*>(&sqb[t][0]) =
        *reinterpret_cast<const int4*>(&qb8[(size_t)c * 8]);
  }
  if (tid == 0) shNc = 0;
  __syncthreads();
  // --- group-expanded scatter: 8 groups x 8 lanes per wave (R6 form)
  {
    const int grp = lane >> 3;   // 0..7: which neighbor within the batch
    const int sub = lane & 7;    // 0..7: offset within the segment
    for (int t0 = 0; t0 < d; t0 += 8) {
      const int t = t0 + grp;
      if (t < d) {
        const int qs = wave ? (int)sqb[t][wave - 1] : 0;
        const int qe = (int)sqb[t][wave];
        const float w = wvals[t];
        const int2* ek = edgesT + (size_t)kcols[t] * MAXD;
        for (int off = qs + sub; off < qe; off += 8) {
          const int2 e = ek[off];
          atomicAdd(&comb[e.x], w * __int_as_float(e.y));
        }
      }
    }
  }
  // --- add row's own attention values (wave's own octant segment)
  {
    const short* qr = qb8 + (size_t)row * 8;
    const int qlo = wave ? (int)qr[wave - 1] : 0;
    const int qhi = (int)qr[wave];
    for (int t = qlo + lane; t < qhi; t += 64) comb[(int)kcols[t]] += wvals[t];
  }
  __syncthreads();
  if (tid == 0) comb[row] = 0.0f;
  __syncthreads();
  const int kk = s2v[row];
  const size_t obase = (size_t)row * NN;
  if (kk <= 0) {
    for (int j = tid * 4; j < NN; j += 2048)
      __builtin_nontemporal_store(z4, reinterpret_cast<f32x4*>(&out1[obase + j]));
  } else {
    // --- pass 0: dense 8-bit radix over comb (zeros skipped; threshold > 0)
    if (tid < 256) hist[tid] = 0u;
    __syncthreads();
    for (int j = tid * 4; j < NN; j += 2048) {
      const f32x4 cv = *reinterpret_cast<const f32x4*>(&comb[j]);
#pragma unroll
      for (int q = 0; q < 4; ++q) {
        const unsigned int u = __float_as_uint(cv[q]);
        if (u != 0u) atomicAdd(&hist[u >> 24], 1u);
      }
    }
    __syncthreads();
    if (tid < 64) {
      const int bHi = 255 - 4 * lane;  // lane 0 owns highest bins
      const unsigned int c0 = hist[bHi];
      const unsigned int c1 = hist[bHi - 1];
      const unsigned int c2 = hist[bHi - 2];
      const unsigned int c3 = hist[bHi - 3];
      const unsigned int gs = c0 + c1 + c2 + c3;
      unsigned int run2 = gs;
      for (int o = 1; o < 64; o <<= 1) {
        const unsigned int tt = __shfl_up(run2, o);
        if (lane >= o) run2 += tt;
      }
      const unsigned int pre = run2 - gs;
      const unsigned int rem = (unsigned int)kk;
      if (pre < rem && pre + gs >= rem) {
        unsigned int above;
        int digit;
        if (pre + c0 >= rem) { digit = bHi; above = pre; }
        else if (pre + c0 + c1 >= rem) { digit = bHi - 1; above = pre + c0; }
        else if (pre + c0 + c1 + c2 >= rem) { digit = bHi - 2; above = pre + c0 + c1; }
        else { digit = bHi - 3; above = pre + c0 + c1 + c2; }
        shPrefix = (unsigned)digit << 24;
        shRemaining = kk - (int)above;
      }
    }
    __syncthreads();
    unsigned int prefix = shPrefix;
    int remaining = shRemaining;
    const unsigned int digit0 = prefix >> 24;
    __syncthreads();
    // --- compact the chosen bin's candidates (order-independent multiset)
    for (int j = tid * 4; j < NN; j += 2048) {
      const f32x4 cv = *reinterpret_cast<const f32x4*>(&comb[j]);
#pragma unroll
      for (int q = 0; q < 4; ++q) {
        const unsigned int u = __float_as_uint(cv[q]);
        if (u != 0u && (u >> 24) == digit0) {
          const int idx = atomicAdd(&shNc, 1);
          if (idx < 512) scomp[idx] = u;
        }
      }
    }
    __syncthreads();
    const int nc = shNc;
    const bool densefb = nc > 512;  // rare fallback
    const unsigned int myu = (!densefb && tid < nc) ? scomp[tid] : 0u;
    for (int pass = 1; pass < 4; ++pass) {
      const int shift = 24 - 8 * pass;
      const unsigned int pmask = 0xFFFFFFFFu << (shift + 8);
      if (tid < 256) hist[tid] = 0u;
      __syncthreads();
      if (!densefb) {
        if (tid < nc && (myu & pmask) == prefix)
          atomicAdd(&hist[(myu >> shift) & 255u], 1u);
      } else {
        for (int j = tid * 4; j < NN; j += 2048) {
          const f32x4 cv = *reinterpret_cast<const f32x4*>(&comb[j]);
#pragma unroll
          for (int q = 0; q < 4; ++q) {
            const unsigned int u = __float_as_uint(cv[q]);
            if (u != 0u && (u & pmask) == prefix)
              atomicAdd(&hist[(u >> shift) & 255u], 1u);
          }
        }
      }
      __syncthreads();
      if (tid < 64) {
        const int bHi = 255 - 4 * lane;
        const unsigned int c0 = hist[bHi];
        const unsigned int c1 = hist[bHi - 1];
        const unsigned int c2 = hist[bHi - 2];
        const unsigned int c3 = hist[bHi - 3];
        const unsigned int gs = c0 + c1 + c2 + c3;
        unsigned int run2 = gs;
        for (int o = 1; o < 64; o <<= 1) {
          const unsigned int tt = __shfl_up(run2, o);
          if (lane >= o) run2 += tt;
        }
        const unsigned int pre = run2 - gs;
        const unsigned int rem = (unsigned int)remaining;
        if (pre < rem && pre + gs >= rem) {
          unsigned int above;
          int digit;
          if (pre + c0 >= rem) { digit = bHi; above = pre; }
          else if (pre + c0 + c1 >= rem) { digit = bHi - 1; above = pre + c0; }
          else if (pre + c0 + c1 + c2 >= rem) { digit = bHi - 2; above = pre + c0 + c1; }
          else { digit = bHi - 3; above = pre + c0 + c1 + c2; }
          shPrefix = prefix | ((unsigned int)digit << shift);
          shRemaining = remaining - (int)above;
        }
      }
      __syncthreads();
      prefix = shPrefix;
      remaining = shRemaining;
      __syncthreads();
    }
    const float thr = __uint_as_float(prefix);  // exact kk-th largest value
    for (int j = tid * 4; j < NN; j += 2048) {
      const f32x4 cv = *reinterpret_cast<const f32x4*>(&comb[j]);
      f32x4 ov;
      ov[0] = (cv[0] >= thr && cv[0] > 0.0f) ? 1.0f : 0.0f;
      ov[1] = (cv[1] >= thr && cv[1] > 0.0f) ? 1.0f : 0.0f;
      ov[2] = (cv[2] >= thr && cv[2] > 0.0f) ? 1.0f : 0.0f;
      ov[3] = (cv[3] >= thr && cv[3] > 0.0f) ? 1.0f : 0.0f;
      __builtin_nontemporal_store(ov, reinterpret_cast<f32x4*>(&out1[obase + j]));
    }
  }
  // --- h_prime at the END: gather overlaps the out1 nt-store drain.
  //     c = tid&255, neighbors t = parity(tid>>8); same order as before.
  float hpacc;
  {
    const int c = tid & 255;
    const int half = tid >> 8;
    float p0 = 0.0f, p1 = 0.0f, p2 = 0.0f, p3 = 0.0f;
    int t = half;
    for (; t + 6 < d; t += 8) {
      p0 += wvals[t]     * Wh[(size_t)kcols[t]     * KFOUT + c];
      p1 += wvals[t + 2] * Wh[(size_t)kcols[t + 2] * KFOUT + c];
      p2 += wvals[t + 4] * Wh[(size_t)kcols[t + 4] * KFOUT + c];
      p3 += wvals[t + 6] * Wh[(size_t)kcols[t + 6] * KFOUT + c];
    }
    for (; t < d; t += 2) p0 += wvals[t] * Wh[(size_t)kcols[t] * KFOUT + c];
    hpacc = (p0 + p1) + (p2 + p3);
  }
  __syncthreads();  // sqb/select buffers all dead; reuse sqb as hp[512]
  float* hp = reinterpret_cast<float*>(&sqb[0][0]);
  hp[tid] = hpacc;
  __syncthreads();
  if (tid < 256) {
    const float acc = hp[tid] + hp[tid + 256];
    const float r = acc > 0.0f ? acc : expm1f(acc);
    __builtin_nontemporal_store(r, &out0[(size_t)row * KFOUT + tid]);
  }
}

extern "C" void kernel_launch(void* const* d_in, const int* in_sizes, int n_in,
                              void* d_out, int out_size, void* d_ws, size_t ws_size,
                              hipStream_t stream) {
  const float* h = (const float*)d_in[0];
  const float* adj = (const float*)d_in[1];
  const float* W = (const float*)d_in[2];
  const float* a = (const float*)d_in[3];

  float* out0 = (float*)d_out;                  // [8192, 256] elu(h_prime)
  float* out1 = out0 + (size_t)NN * KFOUT;      // [8192, 8192] adj_resize

  // workspace layout (~34 MB)
  float* Wh = (float*)d_ws;                        // 8192*256
  float* Wh1 = Wh + (size_t)NN * KFOUT;            // 8192
  float* Wh2 = Wh1 + NN;                           // 8192
  float* mrow = Wh2 + NN;                          // 8192 (unused legacy slot)
  float* Zrow = mrow + NN;                         // 8192 (unused legacy slot)
  float* att = Zrow + NN;                          // 8192*MAXD
  float* edgesF = att + (size_t)NN * MAXD;         // 8192*MAXD int2
  int2* edgesT = (int2*)edgesF;
  int* nbr = (int*)(edgesF + (size_t)NN * MAXD * 2);  // 8192*MAXD
  int* deg = nbr + (size_t)NN * MAXD;              // 8192
  int* s2v = deg + NN;                             // 8192
  short* qb8 = (short*)(s2v + NN);                 // 8192*8 shorts (128 KB)
  float2* mz = (float2*)(qb8 + (size_t)NN * 8);    // 8192 float2 (64 KB)

  k_build_csr<<<NN / 4, 256, 0, stream>>>(adj, nbr, deg, s2v);
  dim3 ggrid(KFOUT / 64, NN / 64);
  k_gemm<<<ggrid, 256, 0, stream>>>(h, W, Wh);
  k_rowdots<<<NN / 4, 256, 0, stream>>>(Wh, a, Wh1, Wh2);
  k_stats<<<NN / 4, 256, 0, stream>>>(nbr, deg, Wh1, Wh2, mz, att, qb8);
  k_att<<<NN / 4, 256, 0, stream>>>(nbr, deg, Wh1, Wh2, mz, edgesT);
  k_twostep<<<NN, 512, 0, stream>>>(nbr, deg, s2v, att, edgesT, qb8, Wh,
                                    out1, out0);
}

// Round 15
// 462.331 us; speedup vs baseline: 1.0049x; 1.0049x over previous
//
#include <hip/hip_runtime.h>
#include <cstdint>
#include <cstddef>

#define NN 8192
#define KFIN 1024
#define KFOUT 256
#define MAXD 192
#define LRALPHA 0.2f

typedef float f32x4 __attribute__((ext_vector_type(4)));

// ---------------------------------------------------------------------------
// Kernel A: dense adj -> CSR neighbor lists (stable ascending-column order via
// 4x ballot on float4 nontemporal loads), degree, s2 = off-diagonal degree.
// ---------------------------------------------------------------------------
__global__ void __launch_bounds__(256) k_build_csr(
    const float* __restrict__ adj, int* __restrict__ nbr,
    int* __restrict__ deg, int* __restrict__ s2v) {
  const int wave = threadIdx.x >> 6;
  const int lane = threadIdx.x & 63;
  const int row = blockIdx.x * 4 + wave;
  const float* arow = adj + (size_t)row * NN;
  int* outp = nbr + (size_t)row * MAXD;
  int count = 0;
  int dflag = 0;
  const unsigned long long below = (1ull << lane) - 1ull;
  for (int c0 = 0; c0 < NN; c0 += 256) {
    const int c = c0 + lane * 4;
    const f32x4 v = __builtin_nontemporal_load(
        reinterpret_cast<const f32x4*>(arow + c));
    const unsigned long long m0 = __ballot(v[0] > 0.0f);
    const unsigned long long m1 = __ballot(v[1] > 0.0f);
    const unsigned long long m2 = __ballot(v[2] > 0.0f);
    const unsigned long long m3 = __ballot(v[3] > 0.0f);
    int pos = count + (int)(__popcll(m0 & below) + __popcll(m1 & below) +
                            __popcll(m2 & below) + __popcll(m3 & below));
    if (v[0] > 0.0f) { if (pos < MAXD) outp[pos] = c + 0; ++pos; if (c + 0 == row) dflag = 1; }
    if (v[1] > 0.0f) { if (pos < MAXD) outp[pos] = c + 1; ++pos; if (c + 1 == row) dflag = 1; }
    if (v[2] > 0.0f) { if (pos < MAXD) outp[pos] = c + 2; ++pos; if (c + 2 == row) dflag = 1; }
    if (v[3] > 0.0f) { if (pos < MAXD) outp[pos] = c + 3; ++pos; if (c + 3 == row) dflag = 1; }
    count += (int)(__popcll(m0) + __popcll(m1) + __popcll(m2) + __popcll(m3));
  }
  const int anyd = __any(dflag) ? 1 : 0;
  if (lane == 0) {
    deg[row] = count < MAXD ? count : MAXD;
    s2v[row] = count - anyd;
  }
}

// ---------------------------------------------------------------------------
// Kernel B: Wh = h @ W, f32 tiled GEMM (64x64 tile, 4x4 per thread, BK=32).
// ---------------------------------------------------------------------------
__global__ void __launch_bounds__(256) k_gemm(
    const float* __restrict__ A, const float* __restrict__ B,
    float* __restrict__ C) {
  __shared__ float As[32][65];
  __shared__ float Bs[32][65];
  const int tid = threadIdx.x;
  const int brow = blockIdx.y * 64;
  const int bcol = blockIdx.x * 64;
  const int tx = tid & 15;
  const int ty = tid >> 4;
  float acc[4][4];
#pragma unroll
  for (int i = 0; i < 4; ++i)
#pragma unroll
    for (int j = 0; j < 4; ++j) acc[i][j] = 0.0f;
  const int ar = tid >> 2;
  const int ac = (tid & 3) << 2;
  const int br = tid >> 4;
  const int bc = (tid & 15) << 2;
  for (int k0 = 0; k0 < KFIN; k0 += 32) {
    const float4 av0 =
        *reinterpret_cast<const float4*>(A + (size_t)(brow + ar) * KFIN + k0 + ac);
    const float4 av1 =
        *reinterpret_cast<const float4*>(A + (size_t)(brow + ar) * KFIN + k0 + 16 + ac);
    const float4 bv0 =
        *reinterpret_cast<const float4*>(B + (size_t)(k0 + br) * KFOUT + bcol + bc);
    const float4 bv1 =
        *reinterpret_cast<const float4*>(B + (size_t)(k0 + 16 + br) * KFOUT + bcol + bc);
    As[ac + 0][ar] = av0.x;
    As[ac + 1][ar] = av0.y;
    As[ac + 2][ar] = av0.z;
    As[ac + 3][ar] = av0.w;
    As[16 + ac + 0][ar] = av1.x;
    As[16 + ac + 1][ar] = av1.y;
    As[16 + ac + 2][ar] = av1.z;
    As[16 + ac + 3][ar] = av1.w;
    Bs[br][bc + 0] = bv0.x;
    Bs[br][bc + 1] = bv0.y;
    Bs[br][bc + 2] = bv0.z;
    Bs[br][bc + 3] = bv0.w;
    Bs[16 + br][bc + 0] = bv1.x;
    Bs[16 + br][bc + 1] = bv1.y;
    Bs[16 + br][bc + 2] = bv1.z;
    Bs[16 + br][bc + 3] = bv1.w;
    __syncthreads();
#pragma unroll
    for (int kk = 0; kk < 32; ++kk) {
      const float a0 = As[kk][ty * 4 + 0];
      const float a1 = As[kk][ty * 4 + 1];
      const float a2 = As[kk][ty * 4 + 2];
      const float a3 = As[kk][ty * 4 + 3];
      const float b0 = Bs[kk][tx * 4 + 0];
      const float b1 = Bs[kk][tx * 4 + 1];
      const float b2 = Bs[kk][tx * 4 + 2];
      const float b3 = Bs[kk][tx * 4 + 3];
      acc[0][0] += a0 * b0; acc[0][1] += a0 * b1; acc[0][2] += a0 * b2; acc[0][3] += a0 * b3;
      acc[1][0] += a1 * b0; acc[1][1] += a1 * b1; acc[1][2] += a1 * b2; acc[1][3] += a1 * b3;
      acc[2][0] += a2 * b0; acc[2][1] += a2 * b1; acc[2][2] += a2 * b2; acc[2][3] += a2 * b3;
      acc[3][0] += a3 * b0; acc[3][1] += a3 * b1; acc[3][2] += a3 * b2; acc[3][3] += a3 * b3;
    }
    __syncthreads();
  }
#pragma unroll
  for (int i = 0; i < 4; ++i) {
#pragma unroll
    for (int j = 0; j < 4; ++j) {
      C[(size_t)(brow + ty * 4 + i) * KFOUT + bcol + tx * 4 + j] = acc[i][j];
    }
  }
}

// ---------------------------------------------------------------------------
// Kernel C: Wh1/Wh2 row dots, one wave per row (shuffle reduce, no barriers).
// ---------------------------------------------------------------------------
__global__ void __launch_bounds__(256) k_rowdots(
    const float* __restrict__ Wh, const float* __restrict__ a,
    float* __restrict__ Wh1, float* __restrict__ Wh2) {
  const int wave = threadIdx.x >> 6;
  const int lane = threadIdx.x & 63;
  const int row = blockIdx.x * 4 + wave;
  const float4 w = *reinterpret_cast<const float4*>(Wh + (size_t)row * KFOUT + lane * 4);
  const float4 aA = *reinterpret_cast<const float4*>(a + lane * 4);
  const float4 aB = *reinterpret_cast<const float4*>(a + KFOUT + lane * 4);
  float sA = w.x * aA.x + w.y * aA.y + w.z * aA.z + w.w * aA.w;
  float sB = w.x * aB.x + w.y * aB.y + w.z * aB.z + w.w * aB.w;
  for (int o = 32; o > 0; o >>= 1) {
    sA += __shfl_xor(sA, o);
    sB += __shfl_xor(sB, o);
  }
  if (lane == 0) {
    Wh1[row] = sA;
    Wh2[row] = sB;
  }
}

// ---------------------------------------------------------------------------
// Kernel D1: per-row softmax stats (m, Z) + row-normalized attention values
// + octant split counts qb8 + packed mz=(m, 1/Z) -- one edge gather.
// ---------------------------------------------------------------------------
__global__ void __launch_bounds__(256) k_stats(
    const int* __restrict__ nbr, const int* __restrict__ deg,
    const float* __restrict__ Wh1, const float* __restrict__ Wh2,
    float2* __restrict__ mz, float* __restrict__ att,
    short* __restrict__ qb8) {
  const int wave = threadIdx.x >> 6;
  const int lane = threadIdx.x & 63;
  const int row = blockIdx.x * 4 + wave;
  const int d = deg[row];
  const size_t rowbase = (size_t)row * MAXD;
  const int* cols = nbr + rowbase;
  const float w1 = Wh1[row];
  int c0 = 0x7fffffff, c1 = 0x7fffffff, c2 = 0x7fffffff;
  float e0 = -1e30f, e1 = -1e30f, e2 = -1e30f;
  const bool a0 = lane < d, a1 = lane + 64 < d, a2 = lane + 128 < d;
  if (a0) { c0 = cols[lane];       float x = w1 + Wh2[c0]; e0 = x > 0.0f ? x : LRALPHA * x; }
  if (a1) { c1 = cols[lane + 64];  float x = w1 + Wh2[c1]; e1 = x > 0.0f ? x : LRALPHA * x; }
  if (a2) { c2 = cols[lane + 128]; float x = w1 + Wh2[c2]; e2 = x > 0.0f ? x : LRALPHA * x; }
  float mx = fmaxf(e0, fmaxf(e1, e2));
  for (int o = 32; o > 0; o >>= 1) mx = fmaxf(mx, __shfl_xor(mx, o));
  const float x0 = a0 ? expf(e0 - mx) : 0.0f;
  const float x1 = a1 ? expf(e1 - mx) : 0.0f;
  const float x2 = a2 ? expf(e2 - mx) : 0.0f;
  float sum = x0 + x1 + x2;
  for (int o = 32; o > 0; o >>= 1) sum += __shfl_xor(sum, o);
  const float Z = (d > 0) ? sum : 1.0f;
  const float invZ = 1.0f / Z;
  if (a0) att[rowbase + lane] = x0 * invZ;
  if (a1) att[rowbase + lane + 64] = x1 * invZ;
  if (a2) att[rowbase + lane + 128] = x2 * invZ;
  int b[7] = {0, 0, 0, 0, 0, 0, 0};
#pragma unroll
  for (int m = 1; m <= 7; ++m) {
    b[m - 1] = (int)__popcll(__ballot(a0 && c0 < m * 1024)) +
               (int)__popcll(__ballot(a1 && c1 < m * 1024)) +
               (int)__popcll(__ballot(a2 && c2 < m * 1024));
  }
  if (lane == 0) {
    mz[row] = make_float2(mx, invZ);
    short* q = qb8 + (size_t)row * 8;
    q[0] = (short)b[0]; q[1] = (short)b[1]; q[2] = (short)b[2]; q[3] = (short)b[3];
    q[4] = (short)b[4]; q[5] = (short)b[5]; q[6] = (short)b[6]; q[7] = (short)d;
  }
}

// ---------------------------------------------------------------------------
// Kernel D2: packed transpose-edge values + h_prime. Runs BEFORE the big
// out1 write stream, so Wh (8 MB) stays L3-resident (memory-side Infinity
// Cache is not yet being flushed by 268 MB of output writes -- R14 lesson).
// Phase 2: one wave per row, lane owns cols 4*lane..4*lane+3; coalesced
// float4 gather of Wh rows, broadcast att weights, ELU, nt store out0.
// ---------------------------------------------------------------------------
__global__ void __launch_bounds__(256) k_att(
    const int* __restrict__ nbr, const int* __restrict__ deg,
    const float* __restrict__ Wh1, const float* __restrict__ Wh2,
    const float2* __restrict__ mz, const float* __restrict__ att,
    const float* __restrict__ Wh, int2* __restrict__ edgesT,
    float* __restrict__ out0) {
  const int wave = threadIdx.x >> 6;
  const int lane = threadIdx.x & 63;
  const int row = blockIdx.x * 4 + wave;
  const int d = deg[row];
  const size_t rowbase = (size_t)row * MAXD;
  const int* cols = nbr + rowbase;
  const float w2r = Wh2[row];
  // phase 1: transpose-edge values
  for (int t = lane; t < d; t += 64) {
    const int j = cols[t];
    float e2 = Wh1[j] + w2r;
    e2 = e2 > 0.0f ? e2 : LRALPHA * e2;
    const float2 m = mz[j];
    const float v = expf(e2 - m.x) * m.y;
    edgesT[rowbase + t] = make_int2(j, __float_as_int(v));
  }
  // phase 2: h_prime row (coalesced Wh float4 gather; 4 partials, t mod 4)
  {
    const float* arow = att + rowbase;
    f32x4 p0 = {0, 0, 0, 0}, p1 = {0, 0, 0, 0};
    f32x4 p2 = {0, 0, 0, 0}, p3 = {0, 0, 0, 0};
    int t = 0;
    for (; t + 3 < d; t += 4) {
      const int j0 = cols[t], j1 = cols[t + 1], j2 = cols[t + 2], j3 = cols[t + 3];
      const float w0 = arow[t], w1 = arow[t + 1], w2 = arow[t + 2], w3 = arow[t + 3];
      const f32x4 a0 = *reinterpret_cast<const f32x4*>(Wh + (size_t)j0 * KFOUT + lane * 4);
      const f32x4 a1 = *reinterpret_cast<const f32x4*>(Wh + (size_t)j1 * KFOUT + lane * 4);
      const f32x4 a2 = *reinterpret_cast<const f32x4*>(Wh + (size_t)j2 * KFOUT + lane * 4);
      const f32x4 a3 = *reinterpret_cast<const f32x4*>(Wh + (size_t)j3 * KFOUT + lane * 4);
      p0 += w0 * a0;
      p1 += w1 * a1;
      p2 += w2 * a2;
      p3 += w3 * a3;
    }
    for (; t < d; ++t) {
      const int j = cols[t];
      const float w = arow[t];
      p0 += w * *reinterpret_cast<const f32x4*>(Wh + (size_t)j * KFOUT + lane * 4);
    }
    const f32x4 r = (p0 + p1) + (p2 + p3);
    f32x4 o;
    o[0] = r[0] > 0.0f ? r[0] : expm1f(r[0]);
    o[1] = r[1] > 0.0f ? r[1] : expm1f(r[1]);
    o[2] = r[2] > 0.0f ? r[2] : expm1f(r[2]);
    o[3] = r[3] > 0.0f ? r[3] : expm1f(r[3]);
    __builtin_nontemporal_store(
        o, reinterpret_cast<f32x4*>(&out0[(size_t)row * KFOUT + lane * 4]));
  }
}

// ---------------------------------------------------------------------------
// Kernel E (R12 form, measured 275us): per row i, 512 threads (8 waves),
// comb in LDS. R6 scatter (octant-partitioned 8-lane group expansion, LDS
// atomics wave-exclusive per octant -> replay-deterministic). Select:
// dense 8-bit pass 0 -> compact candidates -> passes 1-3 on the compact
// array (dense fallback nc>512). Binary row emit with nt stores.
// ---------------------------------------------------------------------------
__global__ void __launch_bounds__(512) k_twostep(
    const int* __restrict__ nbr, const int* __restrict__ deg,
    const int* __restrict__ s2v, const float* __restrict__ att,
    const int2* __restrict__ edgesT, const short* __restrict__ qb8,
    float* __restrict__ out1) {
  __shared__ float comb[NN];                 // 32768 B
  __shared__ float wvals[MAXD];              //   768 B
  __shared__ unsigned short kcols[MAXD];     //   384 B
  __shared__ short sqb[MAXD][8];             //  3072 B
  __shared__ unsigned int hist[256];         //  1024 B
  __shared__ unsigned int scomp[512];        //  2048 B
  __shared__ unsigned int shPrefix;
  __shared__ int shRemaining;
  __shared__ int shNc;
  const int tid = threadIdx.x;
  const int wave = tid >> 6;
  const int lane = tid & 63;
  const int row = blockIdx.x;
  const f32x4 z4 = {0.0f, 0.0f, 0.0f, 0.0f};
  for (int j = tid * 4; j < NN; j += 2048)
    *reinterpret_cast<f32x4*>(&comb[j]) = z4;
  const int d = deg[row];
  const int* cols = nbr + (size_t)row * MAXD;
  const float* arow = att + (size_t)row * MAXD;
  for (int t = tid; t < d; t += 512) {
    const int c = cols[t];
    kcols[t] = (unsigned short)c;
    wvals[t] = arow[t];
    *reinterpret_cast<int4*>(&sqb[t][0]) =
        *reinterpret_cast<const int4*>(&qb8[(size_t)c * 8]);
  }
  if (tid == 0) shNc = 0;
  __syncthreads();
  // --- group-expanded scatter: 8 groups x 8 lanes per wave (R6 form)
  {
    const int grp = lane >> 3;   // 0..7: which neighbor within the batch
    const int sub = lane & 7;    // 0..7: offset within the segment
    for (int t0 = 0; t0 < d; t0 += 8) {
      const int t = t0 + grp;
      if (t < d) {
        const int qs = wave ? (int)sqb[t][wave - 1] : 0;
        const int qe = (int)sqb[t][wave];
        const float w = wvals[t];
        const int2* ek = edgesT + (size_t)kcols[t] * MAXD;
        for (int off = qs + sub; off < qe; off += 8) {
          const int2 e = ek[off];
          atomicAdd(&comb[e.x], w * __int_as_float(e.y));
        }
      }
    }
  }
  // --- add row's own attention values (wave's own octant segment)
  {
    const short* qr = qb8 + (size_t)row * 8;
    const int qlo = wave ? (int)qr[wave - 1] : 0;
    const int qhi = (int)qr[wave];
    for (int t = qlo + lane; t < qhi; t += 64) comb[(int)kcols[t]] += wvals[t];
  }
  __syncthreads();
  if (tid == 0) comb[row] = 0.0f;
  __syncthreads();
  const int kk = s2v[row];
  const size_t obase = (size_t)row * NN;
  if (kk <= 0) {
    for (int j = tid * 4; j < NN; j += 2048)
      __builtin_nontemporal_store(z4, reinterpret_cast<f32x4*>(&out1[obase + j]));
    return;
  }
  // --- pass 0: dense 8-bit radix over comb (zeros skipped; threshold > 0)
  if (tid < 256) hist[tid] = 0u;
  __syncthreads();
  for (int j = tid * 4; j < NN; j += 2048) {
    const f32x4 cv = *reinterpret_cast<const f32x4*>(&comb[j]);
#pragma unroll
    for (int q = 0; q < 4; ++q) {
      const unsigned int u = __float_as_uint(cv[q]);
      if (u != 0u) atomicAdd(&hist[u >> 24], 1u);
    }
  }
  __syncthreads();
  if (tid < 64) {
    const int bHi = 255 - 4 * lane;  // lane 0 owns highest bins
    const unsigned int c0 = hist[bHi];
    const unsigned int c1 = hist[bHi - 1];
    const unsigned int c2 = hist[bHi - 2];
    const unsigned int c3 = hist[bHi - 3];
    const unsigned int gs = c0 + c1 + c2 + c3;
    unsigned int run2 = gs;
    for (int o = 1; o < 64; o <<= 1) {
      const unsigned int tt = __shfl_up(run2, o);
      if (lane >= o) run2 += tt;
    }
    const unsigned int pre = run2 - gs;
    const unsigned int rem = (unsigned int)kk;
    if (pre < rem && pre + gs >= rem) {
      unsigned int above;
      int digit;
      if (pre + c0 >= rem) { digit = bHi; above = pre; }
      else if (pre + c0 + c1 >= rem) { digit = bHi - 1; above = pre + c0; }
      else if (pre + c0 + c1 + c2 >= rem) { digit = bHi - 2; above = pre + c0 + c1; }
      else { digit = bHi - 3; above = pre + c0 + c1 + c2; }
      shPrefix = (unsigned)digit << 24;
      shRemaining = kk - (int)above;
    }
  }
  __syncthreads();
  unsigned int prefix = shPrefix;
  int remaining = shRemaining;
  const unsigned int digit0 = prefix >> 24;
  __syncthreads();
  // --- compact the chosen bin's candidates (order-independent multiset)
  for (int j = tid * 4; j < NN; j += 2048) {
    const f32x4 cv = *reinterpret_cast<const f32x4*>(&comb[j]);
#pragma unroll
    for (int q = 0; q < 4; ++q) {
      const unsigned int u = __float_as_uint(cv[q]);
      if (u != 0u && (u >> 24) == digit0) {
        const int idx = atomicAdd(&shNc, 1);
        if (idx < 512) scomp[idx] = u;
      }
    }
  }
  __syncthreads();
  const int nc = shNc;
  const bool densefb = nc > 512;  // rare fallback
  const unsigned int myu = (!densefb && tid < nc) ? scomp[tid] : 0u;
  // --- passes 1-3: on compact array (or dense comb if fallback)
  for (int pass = 1; pass < 4; ++pass) {
    const int shift = 24 - 8 * pass;
    const unsigned int pmask = 0xFFFFFFFFu << (shift + 8);
    if (tid < 256) hist[tid] = 0u;
    __syncthreads();
    if (!densefb) {
      if (tid < nc && (myu & pmask) == prefix)
        atomicAdd(&hist[(myu >> shift) & 255u], 1u);
    } else {
      for (int j = tid * 4; j < NN; j += 2048) {
        const f32x4 cv = *reinterpret_cast<const f32x4*>(&comb[j]);
#pragma unroll
        for (int q = 0; q < 4; ++q) {
          const unsigned int u = __float_as_uint(cv[q]);
          if (u != 0u && (u & pmask) == prefix)
            atomicAdd(&hist[(u >> shift) & 255u], 1u);
        }
      }
    }
    __syncthreads();
    if (tid < 64) {
      const int bHi = 255 - 4 * lane;
      const unsigned int c0 = hist[bHi];
      const unsigned int c1 = hist[bHi - 1];
      const unsigned int c2 = hist[bHi - 2];
      const unsigned int c3 = hist[bHi - 3];
      const unsigned int gs = c0 + c1 + c2 + c3;
      unsigned int run2 = gs;
      for (int o = 1; o < 64; o <<= 1) {
        const unsigned int tt = __shfl_up(run2, o);
        if (lane >= o) run2 += tt;
      }
      const unsigned int pre = run2 - gs;
      const unsigned int rem = (unsigned int)remaining;
      if (pre < rem && pre + gs >= rem) {
        unsigned int above;
        int digit;
        if (pre + c0 >= rem) { digit = bHi; above = pre; }
        else if (pre + c0 + c1 >= rem) { digit = bHi - 1; above = pre + c0; }
        else if (pre + c0 + c1 + c2 >= rem) { digit = bHi - 2; above = pre + c0 + c1; }
        else { digit = bHi - 3; above = pre + c0 + c1 + c2; }
        shPrefix = prefix | ((unsigned int)digit << shift);
        shRemaining = remaining - (int)above;
      }
    }
    __syncthreads();
    prefix = shPrefix;
    remaining = shRemaining;
    __syncthreads();
  }
  const float thr = __uint_as_float(prefix);  // exact kk-th largest value
  for (int j = tid * 4; j < NN; j += 2048) {
    const f32x4 cv = *reinterpret_cast<const f32x4*>(&comb[j]);
    f32x4 ov;
    ov[0] = (cv[0] >= thr && cv[0] > 0.0f) ? 1.0f : 0.0f;
    ov[1] = (cv[1] >= thr && cv[1] > 0.0f) ? 1.0f : 0.0f;
    ov[2] = (cv[2] >= thr && cv[2] > 0.0f) ? 1.0f : 0.0f;
    ov[3] = (cv[3] >= thr && cv[3] > 0.0f) ? 1.0f : 0.0f;
    __builtin_nontemporal_store(ov, reinterpret_cast<f32x4*>(&out1[obase + j]));
  }
}

extern "C" void kernel_launch(void* const* d_in, const int* in_sizes, int n_in,
                              void* d_out, int out_size, void* d_ws, size_t ws_size,
                              hipStream_t stream) {
  const float* h = (const float*)d_in[0];
  const float* adj = (const float*)d_in[1];
  const float* W = (const float*)d_in[2];
  const float* a = (const float*)d_in[3];

  float* out0 = (float*)d_out;                  // [8192, 256] elu(h_prime)
  float* out1 = out0 + (size_t)NN * KFOUT;      // [8192, 8192] adj_resize

  // workspace layout (~34 MB)
  float* Wh = (float*)d_ws;                        // 8192*256
  float* Wh1 = Wh + (size_t)NN * KFOUT;            // 8192
  float* Wh2 = Wh1 + NN;                           // 8192
  float* mrow = Wh2 + NN;                          // 8192 (unused legacy slot)
  float* Zrow = mrow + NN;                         // 8192 (unused legacy slot)
  float* att = Zrow + NN;                          // 8192*MAXD
  float* edgesF = att + (size_t)NN * MAXD;         // 8192*MAXD int2
  int2* edgesT = (int2*)edgesF;
  int* nbr = (int*)(edgesF + (size_t)NN * MAXD * 2);  // 8192*MAXD
  int* deg = nbr + (size_t)NN * MAXD;              // 8192
  int* s2v = deg + NN;                             // 8192
  short* qb8 = (short*)(s2v + NN);                 // 8192*8 shorts (128 KB)
  float2* mz = (float2*)(qb8 + (size_t)NN * 8);    // 8192 float2 (64 KB)

  k_build_csr<<<NN / 4, 256, 0, stream>>>(adj, nbr, deg, s2v);
  dim3 ggrid(KFOUT / 64, NN / 64);
  k_gemm<<<ggrid, 256, 0, stream>>>(h, W, Wh);
  k_rowdots<<<NN / 4, 256, 0, stream>>>(Wh, a, Wh1, Wh2);
  k_stats<<<NN / 4, 256, 0, stream>>>(nbr, deg, Wh1, Wh2, mz, att, qb8);
  k_att<<<NN / 4, 256, 0, stream>>>(nbr, deg, Wh1, Wh2, mz, att, Wh, edgesT, out0);
  k_twostep<<<NN, 512, 0, stream>>>(nbr, deg, s2v, att, edgesT, qb8, out1);
}

// Round 16
// 452.209 us; speedup vs baseline: 1.0274x; 1.0224x over previous
//
#include <hip/hip_runtime.h>
#include <cstdint>
#include <cstddef>

#define NN 8192
#define KFIN 1024
#define KFOUT 256
#define MAXD 192
#define LRALPHA 0.2f

typedef float f32x4 __attribute__((ext_vector_type(4)));

__device__ __forceinline__ unsigned short bf16_rne(float x) {
  const unsigned u = __float_as_uint(x);
  return (unsigned short)((u + 0x7FFFu + ((u >> 16) & 1u)) >> 16);
}
__device__ __forceinline__ float bf16_to_f32(unsigned short b) {
  return __uint_as_float((unsigned)b << 16);
}

// ---------------------------------------------------------------------------
// Kernel B: Wh = h @ W, f32 tiled GEMM (64x64 tile, 4x4 per thread, BK=32).
// Optionally emits a bf16 (RNE) side-copy Whb for the h_prime gather.
// ---------------------------------------------------------------------------
__global__ void __launch_bounds__(256) k_gemm(
    const float* __restrict__ A, const float* __restrict__ B,
    float* __restrict__ C, unsigned short* __restrict__ Cb) {
  __shared__ float As[32][65];
  __shared__ float Bs[32][65];
  const int tid = threadIdx.x;
  const int brow = blockIdx.y * 64;
  const int bcol = blockIdx.x * 64;
  const int tx = tid & 15;
  const int ty = tid >> 4;
  float acc[4][4];
#pragma unroll
  for (int i = 0; i < 4; ++i)
#pragma unroll
    for (int j = 0; j < 4; ++j) acc[i][j] = 0.0f;
  const int ar = tid >> 2;
  const int ac = (tid & 3) << 2;
  const int br = tid >> 4;
  const int bc = (tid & 15) << 2;
  for (int k0 = 0; k0 < KFIN; k0 += 32) {
    const float4 av0 =
        *reinterpret_cast<const float4*>(A + (size_t)(brow + ar) * KFIN + k0 + ac);
    const float4 av1 =
        *reinterpret_cast<const float4*>(A + (size_t)(brow + ar) * KFIN + k0 + 16 + ac);
    const float4 bv0 =
        *reinterpret_cast<const float4*>(B + (size_t)(k0 + br) * KFOUT + bcol + bc);
    const float4 bv1 =
        *reinterpret_cast<const float4*>(B + (size_t)(k0 + 16 + br) * KFOUT + bcol + bc);
    As[ac + 0][ar] = av0.x;
    As[ac + 1][ar] = av0.y;
    As[ac + 2][ar] = av0.z;
    As[ac + 3][ar] = av0.w;
    As[16 + ac + 0][ar] = av1.x;
    As[16 + ac + 1][ar] = av1.y;
    As[16 + ac + 2][ar] = av1.z;
    As[16 + ac + 3][ar] = av1.w;
    Bs[br][bc + 0] = bv0.x;
    Bs[br][bc + 1] = bv0.y;
    Bs[br][bc + 2] = bv0.z;
    Bs[br][bc + 3] = bv0.w;
    Bs[16 + br][bc + 0] = bv1.x;
    Bs[16 + br][bc + 1] = bv1.y;
    Bs[16 + br][bc + 2] = bv1.z;
    Bs[16 + br][bc + 3] = bv1.w;
    __syncthreads();
#pragma unroll
    for (int kk = 0; kk < 32; ++kk) {
      const float a0 = As[kk][ty * 4 + 0];
      const float a1 = As[kk][ty * 4 + 1];
      const float a2 = As[kk][ty * 4 + 2];
      const float a3 = As[kk][ty * 4 + 3];
      const float b0 = Bs[kk][tx * 4 + 0];
      const float b1 = Bs[kk][tx * 4 + 1];
      const float b2 = Bs[kk][tx * 4 + 2];
      const float b3 = Bs[kk][tx * 4 + 3];
      acc[0][0] += a0 * b0; acc[0][1] += a0 * b1; acc[0][2] += a0 * b2; acc[0][3] += a0 * b3;
      acc[1][0] += a1 * b0; acc[1][1] += a1 * b1; acc[1][2] += a1 * b2; acc[1][3] += a1 * b3;
      acc[2][0] += a2 * b0; acc[2][1] += a2 * b1; acc[2][2] += a2 * b2; acc[2][3] += a2 * b3;
      acc[3][0] += a3 * b0; acc[3][1] += a3 * b1; acc[3][2] += a3 * b2; acc[3][3] += a3 * b3;
    }
    __syncthreads();
  }
#pragma unroll
  for (int i = 0; i < 4; ++i) {
#pragma unroll
    for (int j = 0; j < 4; ++j) {
      const size_t idx = (size_t)(brow + ty * 4 + i) * KFOUT + bcol + tx * 4 + j;
      C[idx] = acc[i][j];
      if (Cb) Cb[idx] = bf16_rne(acc[i][j]);
    }
  }
}

// ---------------------------------------------------------------------------
// Kernel C: Wh1/Wh2 row dots, one wave per row (shuffle reduce, no barriers).
// ---------------------------------------------------------------------------
__global__ void __launch_bounds__(256) k_rowdots(
    const float* __restrict__ Wh, const float* __restrict__ a,
    float* __restrict__ Wh1, float* __restrict__ Wh2) {
  const int wave = threadIdx.x >> 6;
  const int lane = threadIdx.x & 63;
  const int row = blockIdx.x * 4 + wave;
  const float4 w = *reinterpret_cast<const float4*>(Wh + (size_t)row * KFOUT + lane * 4);
  const float4 aA = *reinterpret_cast<const float4*>(a + lane * 4);
  const float4 aB = *reinterpret_cast<const float4*>(a + KFOUT + lane * 4);
  float sA = w.x * aA.x + w.y * aA.y + w.z * aA.z + w.w * aA.w;
  float sB = w.x * aB.x + w.y * aB.y + w.z * aB.z + w.w * aB.w;
  for (int o = 32; o > 0; o >>= 1) {
    sA += __shfl_xor(sA, o);
    sB += __shfl_xor(sB, o);
  }
  if (lane == 0) {
    Wh1[row] = sA;
    Wh2[row] = sB;
  }
}

// ---------------------------------------------------------------------------
// Kernel A+D1 fused: CSR build (ballot compaction, ascending cols) + octant
// counts as `count` snapshots at 1024-boundaries + per-row softmax stats
// (m, Z), row-normalized attention values, packed mz=(m,1/Z), qb8.
// Runs AFTER gemm+rowdots (needs Wh1/Wh2). One wave per row.
// ---------------------------------------------------------------------------
__global__ void __launch_bounds__(256) k_csr_stats(
    const float* __restrict__ adj, const float* __restrict__ Wh1,
    const float* __restrict__ Wh2, int* __restrict__ nbr,
    int* __restrict__ deg, int* __restrict__ s2v,
    float2* __restrict__ mz, float* __restrict__ att,
    short* __restrict__ qb8) {
  const int wave = threadIdx.x >> 6;
  const int lane = threadIdx.x & 63;
  const int row = blockIdx.x * 4 + wave;
  const float* arow = adj + (size_t)row * NN;
  int* outp = nbr + (size_t)row * MAXD;
  int count = 0;
  int dflag = 0;
  int b[7];
  const unsigned long long below = (1ull << lane) - 1ull;
  for (int c0 = 0; c0 < NN; c0 += 256) {
    if (c0 > 0 && (c0 & 1023) == 0) b[(c0 >> 10) - 1] = count;
    const int c = c0 + lane * 4;
    const f32x4 v = __builtin_nontemporal_load(
        reinterpret_cast<const f32x4*>(arow + c));
    const unsigned long long m0 = __ballot(v[0] > 0.0f);
    const unsigned long long m1 = __ballot(v[1] > 0.0f);
    const unsigned long long m2 = __ballot(v[2] > 0.0f);
    const unsigned long long m3 = __ballot(v[3] > 0.0f);
    int pos = count + (int)(__popcll(m0 & below) + __popcll(m1 & below) +
                            __popcll(m2 & below) + __popcll(m3 & below));
    if (v[0] > 0.0f) { if (pos < MAXD) outp[pos] = c + 0; ++pos; if (c + 0 == row) dflag = 1; }
    if (v[1] > 0.0f) { if (pos < MAXD) outp[pos] = c + 1; ++pos; if (c + 1 == row) dflag = 1; }
    if (v[2] > 0.0f) { if (pos < MAXD) outp[pos] = c + 2; ++pos; if (c + 2 == row) dflag = 1; }
    if (v[3] > 0.0f) { if (pos < MAXD) outp[pos] = c + 3; ++pos; if (c + 3 == row) dflag = 1; }
    count += (int)(__popcll(m0) + __popcll(m1) + __popcll(m2) + __popcll(m3));
  }
  const int anyd = __any(dflag) ? 1 : 0;
  const int d = count < MAXD ? count : MAXD;
  if (lane == 0) {
    deg[row] = d;
    s2v[row] = count - anyd;
    short* q = qb8 + (size_t)row * 8;
#pragma unroll
    for (int w = 0; w < 7; ++w) {
      const int bw = b[w] < d ? b[w] : d;
      q[w] = (short)bw;
    }
    q[7] = (short)d;
  }
  // --- stats phase (cols just written by this wave; RAW through L2 is
  //     wave-local and the compiler inserts the vmcnt waits)
  const size_t rowbase = (size_t)row * MAXD;
  const int* cols = outp;
  const float w1 = Wh1[row];
  int c0i = 0x7fffffff, c1i = 0x7fffffff, c2i = 0x7fffffff;
  float e0 = -1e30f, e1 = -1e30f, e2 = -1e30f;
  const bool a0 = lane < d, a1 = lane + 64 < d, a2 = lane + 128 < d;
  if (a0) { c0i = cols[lane];       float x = w1 + Wh2[c0i]; e0 = x > 0.0f ? x : LRALPHA * x; }
  if (a1) { c1i = cols[lane + 64];  float x = w1 + Wh2[c1i]; e1 = x > 0.0f ? x : LRALPHA * x; }
  if (a2) { c2i = cols[lane + 128]; float x = w1 + Wh2[c2i]; e2 = x > 0.0f ? x : LRALPHA * x; }
  float mx = fmaxf(e0, fmaxf(e1, e2));
  for (int o = 32; o > 0; o >>= 1) mx = fmaxf(mx, __shfl_xor(mx, o));
  const float x0 = a0 ? expf(e0 - mx) : 0.0f;
  const float x1 = a1 ? expf(e1 - mx) : 0.0f;
  const float x2 = a2 ? expf(e2 - mx) : 0.0f;
  float sum = x0 + x1 + x2;
  for (int o = 32; o > 0; o >>= 1) sum += __shfl_xor(sum, o);
  const float Z = (d > 0) ? sum : 1.0f;
  const float invZ = 1.0f / Z;
  if (a0) att[rowbase + lane] = x0 * invZ;
  if (a1) att[rowbase + lane + 64] = x1 * invZ;
  if (a2) att[rowbase + lane + 128] = x2 * invZ;
  if (lane == 0) mz[row] = make_float2(mx, invZ);
}

// ---------------------------------------------------------------------------
// Kernel D2: packed transpose-edge values + h_prime (before the big out1
// write stream so Wh stays L3-resident -- R14 lesson). Phase 2 uses the bf16
// Whb copy when available (halves the 546 MB logical gather), else f32 Wh.
// ---------------------------------------------------------------------------
__global__ void __launch_bounds__(256) k_att(
    const int* __restrict__ nbr, const int* __restrict__ deg,
    const float* __restrict__ Wh1, const float* __restrict__ Wh2,
    const float2* __restrict__ mz, const float* __restrict__ att,
    const float* __restrict__ Wh, const unsigned short* __restrict__ Whb,
    int2* __restrict__ edgesT, float* __restrict__ out0) {
  const int wave = threadIdx.x >> 6;
  const int lane = threadIdx.x & 63;
  const int row = blockIdx.x * 4 + wave;
  const int d = deg[row];
  const size_t rowbase = (size_t)row * MAXD;
  const int* cols = nbr + rowbase;
  const float w2r = Wh2[row];
  // phase 1: transpose-edge values
  for (int t = lane; t < d; t += 64) {
    const int j = cols[t];
    float e2 = Wh1[j] + w2r;
    e2 = e2 > 0.0f ? e2 : LRALPHA * e2;
    const float2 m = mz[j];
    const float v = expf(e2 - m.x) * m.y;
    edgesT[rowbase + t] = make_int2(j, __float_as_int(v));
  }
  // phase 2: h_prime row (coalesced gather; 4 partials, t mod 4)
  {
    const float* arow = att + rowbase;
    f32x4 p0 = {0, 0, 0, 0}, p1 = {0, 0, 0, 0};
    f32x4 p2 = {0, 0, 0, 0}, p3 = {0, 0, 0, 0};
    int t = 0;
    if (Whb) {
      for (; t + 3 < d; t += 4) {
        const int j0 = cols[t], j1 = cols[t + 1], j2 = cols[t + 2], j3 = cols[t + 3];
        const float w0 = arow[t], w1 = arow[t + 1], w2 = arow[t + 2], w3 = arow[t + 3];
        const ushort4 b0 = *reinterpret_cast<const ushort4*>(Whb + (size_t)j0 * KFOUT + lane * 4);
        const ushort4 b1 = *reinterpret_cast<const ushort4*>(Whb + (size_t)j1 * KFOUT + lane * 4);
        const ushort4 b2 = *reinterpret_cast<const ushort4*>(Whb + (size_t)j2 * KFOUT + lane * 4);
        const ushort4 b3 = *reinterpret_cast<const ushort4*>(Whb + (size_t)j3 * KFOUT + lane * 4);
        const f32x4 a0 = {bf16_to_f32(b0.x), bf16_to_f32(b0.y), bf16_to_f32(b0.z), bf16_to_f32(b0.w)};
        const f32x4 a1 = {bf16_to_f32(b1.x), bf16_to_f32(b1.y), bf16_to_f32(b1.z), bf16_to_f32(b1.w)};
        const f32x4 a2 = {bf16_to_f32(b2.x), bf16_to_f32(b2.y), bf16_to_f32(b2.z), bf16_to_f32(b2.w)};
        const f32x4 a3 = {bf16_to_f32(b3.x), bf16_to_f32(b3.y), bf16_to_f32(b3.z), bf16_to_f32(b3.w)};
        p0 += w0 * a0;
        p1 += w1 * a1;
        p2 += w2 * a2;
        p3 += w3 * a3;
      }
      for (; t < d; ++t) {
        const int j = cols[t];
        const float w = arow[t];
        const ushort4 b = *reinterpret_cast<const ushort4*>(Whb + (size_t)j * KFOUT + lane * 4);
        const f32x4 av = {bf16_to_f32(b.x), bf16_to_f32(b.y), bf16_to_f32(b.z), bf16_to_f32(b.w)};
        p0 += w * av;
      }
    } else {
      for (; t + 3 < d; t += 4) {
        const int j0 = cols[t], j1 = cols[t + 1], j2 = cols[t + 2], j3 = cols[t + 3];
        const float w0 = arow[t], w1 = arow[t + 1], w2 = arow[t + 2], w3 = arow[t + 3];
        const f32x4 a0 = *reinterpret_cast<const f32x4*>(Wh + (size_t)j0 * KFOUT + lane * 4);
        const f32x4 a1 = *reinterpret_cast<const f32x4*>(Wh + (size_t)j1 * KFOUT + lane * 4);
        const f32x4 a2 = *reinterpret_cast<const f32x4*>(Wh + (size_t)j2 * KFOUT + lane * 4);
        const f32x4 a3 = *reinterpret_cast<const f32x4*>(Wh + (size_t)j3 * KFOUT + lane * 4);
        p0 += w0 * a0;
        p1 += w1 * a1;
        p2 += w2 * a2;
        p3 += w3 * a3;
      }
      for (; t < d; ++t) {
        const int j = cols[t];
        const float w = arow[t];
        p0 += w * *reinterpret_cast<const f32x4*>(Wh + (size_t)j * KFOUT + lane * 4);
      }
    }
    const f32x4 r = (p0 + p1) + (p2 + p3);
    f32x4 o;
    o[0] = r[0] > 0.0f ? r[0] : expm1f(r[0]);
    o[1] = r[1] > 0.0f ? r[1] : expm1f(r[1]);
    o[2] = r[2] > 0.0f ? r[2] : expm1f(r[2]);
    o[3] = r[3] > 0.0f ? r[3] : expm1f(r[3]);
    __builtin_nontemporal_store(
        o, reinterpret_cast<f32x4*>(&out0[(size_t)row * KFOUT + lane * 4]));
  }
}

// ---------------------------------------------------------------------------
// Kernel E (R12/R15 form, measured 275us): per row i, 512 threads (8 waves),
// comb in LDS. R6 scatter (octant-partitioned 8-lane group expansion, LDS
// atomics wave-exclusive per octant -> replay-deterministic). Select:
// dense 8-bit pass 0 -> compact candidates -> passes 1-3 on the compact
// array (dense fallback nc>512). Binary row emit with nt stores.
// ---------------------------------------------------------------------------
__global__ void __launch_bounds__(512) k_twostep(
    const int* __restrict__ nbr, const int* __restrict__ deg,
    const int* __restrict__ s2v, const float* __restrict__ att,
    const int2* __restrict__ edgesT, const short* __restrict__ qb8,
    float* __restrict__ out1) {
  __shared__ float comb[NN];                 // 32768 B
  __shared__ float wvals[MAXD];              //   768 B
  __shared__ unsigned short kcols[MAXD];     //   384 B
  __shared__ short sqb[MAXD][8];             //  3072 B
  __shared__ unsigned int hist[256];         //  1024 B
  __shared__ unsigned int scomp[512];        //  2048 B
  __shared__ unsigned int shPrefix;
  __shared__ int shRemaining;
  __shared__ int shNc;
  const int tid = threadIdx.x;
  const int wave = tid >> 6;
  const int lane = tid & 63;
  const int row = blockIdx.x;
  const f32x4 z4 = {0.0f, 0.0f, 0.0f, 0.0f};
  for (int j = tid * 4; j < NN; j += 2048)
    *reinterpret_cast<f32x4*>(&comb[j]) = z4;
  const int d = deg[row];
  const int* cols = nbr + (size_t)row * MAXD;
  const float* arow = att + (size_t)row * MAXD;
  for (int t = tid; t < d; t += 512) {
    const int c = cols[t];
    kcols[t] = (unsigned short)c;
    wvals[t] = arow[t];
    *reinterpret_cast<int4*>(&sqb[t][0]) =
        *reinterpret_cast<const int4*>(&qb8[(size_t)c * 8]);
  }
  if (tid == 0) shNc = 0;
  __syncthreads();
  // --- group-expanded scatter: 8 groups x 8 lanes per wave (R6 form)
  {
    const int grp = lane >> 3;   // 0..7: which neighbor within the batch
    const int sub = lane & 7;    // 0..7: offset within the segment
    for (int t0 = 0; t0 < d; t0 += 8) {
      const int t = t0 + grp;
      if (t < d) {
        const int qs = wave ? (int)sqb[t][wave - 1] : 0;
        const int qe = (int)sqb[t][wave];
        const float w = wvals[t];
        const int2* ek = edgesT + (size_t)kcols[t] * MAXD;
        for (int off = qs + sub; off < qe; off += 8) {
          const int2 e = ek[off];
          atomicAdd(&comb[e.x], w * __int_as_float(e.y));
        }
      }
    }
  }
  // --- add row's own attention values (wave's own octant segment)
  {
    const short* qr = qb8 + (size_t)row * 8;
    const int qlo = wave ? (int)qr[wave - 1] : 0;
    const int qhi = (int)qr[wave];
    for (int t = qlo + lane; t < qhi; t += 64) comb[(int)kcols[t]] += wvals[t];
  }
  __syncthreads();
  if (tid == 0) comb[row] = 0.0f;
  __syncthreads();
  const int kk = s2v[row];
  const size_t obase = (size_t)row * NN;
  if (kk <= 0) {
    for (int j = tid * 4; j < NN; j += 2048)
      __builtin_nontemporal_store(z4, reinterpret_cast<f32x4*>(&out1[obase + j]));
    return;
  }
  // --- pass 0: dense 8-bit radix over comb (zeros skipped; threshold > 0)
  if (tid < 256) hist[tid] = 0u;
  __syncthreads();
  for (int j = tid * 4; j < NN; j += 2048) {
    const f32x4 cv = *reinterpret_cast<const f32x4*>(&comb[j]);
#pragma unroll
    for (int q = 0; q < 4; ++q) {
      const unsigned int u = __float_as_uint(cv[q]);
      if (u != 0u) atomicAdd(&hist[u >> 24], 1u);
    }
  }
  __syncthreads();
  if (tid < 64) {
    const int bHi = 255 - 4 * lane;  // lane 0 owns highest bins
    const unsigned int c0 = hist[bHi];
    const unsigned int c1 = hist[bHi - 1];
    const unsigned int c2 = hist[bHi - 2];
    const unsigned int c3 = hist[bHi - 3];
    const unsigned int gs = c0 + c1 + c2 + c3;
    unsigned int run2 = gs;
    for (int o = 1; o < 64; o <<= 1) {
      const unsigned int tt = __shfl_up(run2, o);
      if (lane >= o) run2 += tt;
    }
    const unsigned int pre = run2 - gs;
    const unsigned int rem = (unsigned int)kk;
    if (pre < rem && pre + gs >= rem) {
      unsigned int above;
      int digit;
      if (pre + c0 >= rem) { digit = bHi; above = pre; }
      else if (pre + c0 + c1 >= rem) { digit = bHi - 1; above = pre + c0; }
      else if (pre + c0 + c1 + c2 >= rem) { digit = bHi - 2; above = pre + c0 + c1; }
      else { digit = bHi - 3; above = pre + c0 + c1 + c2; }
      shPrefix = (unsigned)digit << 24;
      shRemaining = kk - (int)above;
    }
  }
  __syncthreads();
  unsigned int prefix = shPrefix;
  int remaining = shRemaining;
  const unsigned int digit0 = prefix >> 24;
  __syncthreads();
  // --- compact the chosen bin's candidates (order-independent multiset)
  for (int j = tid * 4; j < NN; j += 2048) {
    const f32x4 cv = *reinterpret_cast<const f32x4*>(&comb[j]);
#pragma unroll
    for (int q = 0; q < 4; ++q) {
      const unsigned int u = __float_as_uint(cv[q]);
      if (u != 0u && (u >> 24) == digit0) {
        const int idx = atomicAdd(&shNc, 1);
        if (idx < 512) scomp[idx] = u;
      }
    }
  }
  __syncthreads();
  const int nc = shNc;
  const bool densefb = nc > 512;  // rare fallback
  const unsigned int myu = (!densefb && tid < nc) ? scomp[tid] : 0u;
  // --- passes 1-3: on compact array (or dense comb if fallback)
  for (int pass = 1; pass < 4; ++pass) {
    const int shift = 24 - 8 * pass;
    const unsigned int pmask = 0xFFFFFFFFu << (shift + 8);
    if (tid < 256) hist[tid] = 0u;
    __syncthreads();
    if (!densefb) {
      if (tid < nc && (myu & pmask) == prefix)
        atomicAdd(&hist[(myu >> shift) & 255u], 1u);
    } else {
      for (int j = tid * 4; j < NN; j += 2048) {
        const f32x4 cv = *reinterpret_cast<const f32x4*>(&comb[j]);
#pragma unroll
        for (int q = 0; q < 4; ++q) {
          const unsigned int u = __float_as_uint(cv[q]);
          if (u != 0u && (u & pmask) == prefix)
            atomicAdd(&hist[(u >> shift) & 255u], 1u);
        }
      }
    }
    __syncthreads();
    if (tid < 64) {
      const int bHi = 255 - 4 * lane;
      const unsigned int c0 = hist[bHi];
      const unsigned int c1 = hist[bHi - 1];
      const unsigned int c2 = hist[bHi - 2];
      const unsigned int c3 = hist[bHi - 3];
      const unsigned int gs = c0 + c1 + c2 + c3;
      unsigned int run2 = gs;
      for (int o = 1; o < 64; o <<= 1) {
        const unsigned int tt = __shfl_up(run2, o);
        if (lane >= o) run2 += tt;
      }
      const unsigned int pre = run2 - gs;
      const unsigned int rem = (unsigned int)remaining;
      if (pre < rem && pre + gs >= rem) {
        unsigned int above;
        int digit;
        if (pre + c0 >= rem) { digit = bHi; above = pre; }
        else if (pre + c0 + c1 >= rem) { digit = bHi - 1; above = pre + c0; }
        else if (pre + c0 + c1 + c2 >= rem) { digit = bHi - 2; above = pre + c0 + c1; }
        else { digit = bHi - 3; above = pre + c0 + c1 + c2; }
        shPrefix = prefix | ((unsigned int)digit << shift);
        shRemaining = remaining - (int)above;
      }
    }
    __syncthreads();
    prefix = shPrefix;
    remaining = shRemaining;
    __syncthreads();
  }
  const float thr = __uint_as_float(prefix);  // exact kk-th largest value
  for (int j = tid * 4; j < NN; j += 2048) {
    const f32x4 cv = *reinterpret_cast<const f32x4*>(&comb[j]);
    f32x4 ov;
    ov[0] = (cv[0] >= thr && cv[0] > 0.0f) ? 1.0f : 0.0f;
    ov[1] = (cv[1] >= thr && cv[1] > 0.0f) ? 1.0f : 0.0f;
    ov[2] = (cv[2] >= thr && cv[2] > 0.0f) ? 1.0f : 0.0f;
    ov[3] = (cv[3] >= thr && cv[3] > 0.0f) ? 1.0f : 0.0f;
    __builtin_nontemporal_store(ov, reinterpret_cast<f32x4*>(&out1[obase + j]));
  }
}

extern "C" void kernel_launch(void* const* d_in, const int* in_sizes, int n_in,
                              void* d_out, int out_size, void* d_ws, size_t ws_size,
                              hipStream_t stream) {
  const float* h = (const float*)d_in[0];
  const float* adj = (const float*)d_in[1];
  const float* W = (const float*)d_in[2];
  const float* a = (const float*)d_in[3];

  float* out0 = (float*)d_out;                  // [8192, 256] elu(h_prime)
  float* out1 = out0 + (size_t)NN * KFOUT;      // [8192, 8192] adj_resize

  // workspace layout (~34 MB base, +4 MB Whb if room)
  float* Wh = (float*)d_ws;                        // 8192*256
  float* Wh1 = Wh + (size_t)NN * KFOUT;            // 8192
  float* Wh2 = Wh1 + NN;                           // 8192
  float* mrow = Wh2 + NN;                          // 8192 (unused legacy slot)
  float* Zrow = mrow + NN;                         // 8192 (unused legacy slot)
  float* att = Zrow + NN;                          // 8192*MAXD
  float* edgesF = att + (size_t)NN * MAXD;         // 8192*MAXD int2
  int2* edgesT = (int2*)edgesF;
  int* nbr = (int*)(edgesF + (size_t)NN * MAXD * 2);  // 8192*MAXD
  int* deg = nbr + (size_t)NN * MAXD;              // 8192
  int* s2v = deg + NN;                             // 8192
  short* qb8 = (short*)(s2v + NN);                 // 8192*8 shorts (128 KB)
  float2* mz = (float2*)(qb8 + (size_t)NN * 8);    // 8192 float2 (64 KB)
  unsigned short* Whb = (unsigned short*)(mz + NN);  // 8192*256 u16 (4 MB)
  const size_t need =
      (size_t)((char*)(Whb + (size_t)NN * KFOUT) - (char*)d_ws);
  const bool useB = ws_size >= need;
  unsigned short* WhbArg = useB ? Whb : nullptr;

  dim3 ggrid(KFOUT / 64, NN / 64);
  k_gemm<<<ggrid, 256, 0, stream>>>(h, W, Wh, WhbArg);
  k_rowdots<<<NN / 4, 256, 0, stream>>>(Wh, a, Wh1, Wh2);
  k_csr_stats<<<NN / 4, 256, 0, stream>>>(adj, Wh1, Wh2, nbr, deg, s2v, mz,
                                          att, qb8);
  k_att<<<NN / 4, 256, 0, stream>>>(nbr, deg, Wh1, Wh2, mz, att, Wh, WhbArg,
                                    edgesT, out0);
  k_twostep<<<NN, 512, 0, stream>>>(nbr, deg, s2v, att, edgesT, qb8, out1);
}

// Round 17
// 451.996 us; speedup vs baseline: 1.0279x; 1.0005x over previous
//
#include <hip/hip_runtime.h>
#include <cstdint>
#include <cstddef>

#define NN 8192
#define KFIN 1024
#define KFOUT 256
#define MAXD 192
#define LRALPHA 0.2f

typedef float f32x4 __attribute__((ext_vector_type(4)));

__device__ __forceinline__ unsigned short bf16_rne(float x) {
  const unsigned u = __float_as_uint(x);
  return (unsigned short)((u + 0x7FFFu + ((u >> 16) & 1u)) >> 16);
}
__device__ __forceinline__ float bf16_to_f32(unsigned short b) {
  return __uint_as_float((unsigned)b << 16);
}

// ---------------------------------------------------------------------------
// Kernel B: Wh = h @ W, f32 tiled GEMM (64x64 tile, 4x4 per thread, BK=32).
// Emits a bf16 (RNE) side-copy Whb for the h_prime gather.
// ---------------------------------------------------------------------------
__global__ void __launch_bounds__(256) k_gemm(
    const float* __restrict__ A, const float* __restrict__ B,
    float* __restrict__ C, unsigned short* __restrict__ Cb) {
  __shared__ float As[32][65];
  __shared__ float Bs[32][65];
  const int tid = threadIdx.x;
  const int brow = blockIdx.y * 64;
  const int bcol = blockIdx.x * 64;
  const int tx = tid & 15;
  const int ty = tid >> 4;
  float acc[4][4];
#pragma unroll
  for (int i = 0; i < 4; ++i)
#pragma unroll
    for (int j = 0; j < 4; ++j) acc[i][j] = 0.0f;
  const int ar = tid >> 2;
  const int ac = (tid & 3) << 2;
  const int br = tid >> 4;
  const int bc = (tid & 15) << 2;
  for (int k0 = 0; k0 < KFIN; k0 += 32) {
    const float4 av0 =
        *reinterpret_cast<const float4*>(A + (size_t)(brow + ar) * KFIN + k0 + ac);
    const float4 av1 =
        *reinterpret_cast<const float4*>(A + (size_t)(brow + ar) * KFIN + k0 + 16 + ac);
    const float4 bv0 =
        *reinterpret_cast<const float4*>(B + (size_t)(k0 + br) * KFOUT + bcol + bc);
    const float4 bv1 =
        *reinterpret_cast<const float4*>(B + (size_t)(k0 + 16 + br) * KFOUT + bcol + bc);
    As[ac + 0][ar] = av0.x;
    As[ac + 1][ar] = av0.y;
    As[ac + 2][ar] = av0.z;
    As[ac + 3][ar] = av0.w;
    As[16 + ac + 0][ar] = av1.x;
    As[16 + ac + 1][ar] = av1.y;
    As[16 + ac + 2][ar] = av1.z;
    As[16 + ac + 3][ar] = av1.w;
    Bs[br][bc + 0] = bv0.x;
    Bs[br][bc + 1] = bv0.y;
    Bs[br][bc + 2] = bv0.z;
    Bs[br][bc + 3] = bv0.w;
    Bs[16 + br][bc + 0] = bv1.x;
    Bs[16 + br][bc + 1] = bv1.y;
    Bs[16 + br][bc + 2] = bv1.z;
    Bs[16 + br][bc + 3] = bv1.w;
    __syncthreads();
#pragma unroll
    for (int kk = 0; kk < 32; ++kk) {
      const float a0 = As[kk][ty * 4 + 0];
      const float a1 = As[kk][ty * 4 + 1];
      const float a2 = As[kk][ty * 4 + 2];
      const float a3 = As[kk][ty * 4 + 3];
      const float b0 = Bs[kk][tx * 4 + 0];
      const float b1 = Bs[kk][tx * 4 + 1];
      const float b2 = Bs[kk][tx * 4 + 2];
      const float b3 = Bs[kk][tx * 4 + 3];
      acc[0][0] += a0 * b0; acc[0][1] += a0 * b1; acc[0][2] += a0 * b2; acc[0][3] += a0 * b3;
      acc[1][0] += a1 * b0; acc[1][1] += a1 * b1; acc[1][2] += a1 * b2; acc[1][3] += a1 * b3;
      acc[2][0] += a2 * b0; acc[2][1] += a2 * b1; acc[2][2] += a2 * b2; acc[2][3] += a2 * b3;
      acc[3][0] += a3 * b0; acc[3][1] += a3 * b1; acc[3][2] += a3 * b2; acc[3][3] += a3 * b3;
    }
    __syncthreads();
  }
#pragma unroll
  for (int i = 0; i < 4; ++i) {
#pragma unroll
    for (int j = 0; j < 4; ++j) {
      const size_t idx = (size_t)(brow + ty * 4 + i) * KFOUT + bcol + tx * 4 + j;
      C[idx] = acc[i][j];
      if (Cb) Cb[idx] = bf16_rne(acc[i][j]);
    }
  }
}

// ---------------------------------------------------------------------------
// Kernel C: Wh1/Wh2 row dots, one wave per row (shuffle reduce, no barriers).
// ---------------------------------------------------------------------------
__global__ void __launch_bounds__(256) k_rowdots(
    const float* __restrict__ Wh, const float* __restrict__ a,
    float* __restrict__ Wh1, float* __restrict__ Wh2) {
  const int wave = threadIdx.x >> 6;
  const int lane = threadIdx.x & 63;
  const int row = blockIdx.x * 4 + wave;
  const float4 w = *reinterpret_cast<const float4*>(Wh + (size_t)row * KFOUT + lane * 4);
  const float4 aA = *reinterpret_cast<const float4*>(a + lane * 4);
  const float4 aB = *reinterpret_cast<const float4*>(a + KFOUT + lane * 4);
  float sA = w.x * aA.x + w.y * aA.y + w.z * aA.z + w.w * aA.w;
  float sB = w.x * aB.x + w.y * aB.y + w.z * aB.z + w.w * aB.w;
  for (int o = 32; o > 0; o >>= 1) {
    sA += __shfl_xor(sA, o);
    sB += __shfl_xor(sB, o);
  }
  if (lane == 0) {
    Wh1[row] = sA;
    Wh2[row] = sB;
  }
}

// ---------------------------------------------------------------------------
// Kernel A+D1 fused: CSR build + octant counts (snapshots at 1024-boundaries)
// + per-row softmax stats (m, Z), attention values, mz, qb8. One wave/row.
// ---------------------------------------------------------------------------
__global__ void __launch_bounds__(256) k_csr_stats(
    const float* __restrict__ adj, const float* __restrict__ Wh1,
    const float* __restrict__ Wh2, int* __restrict__ nbr,
    int* __restrict__ deg, int* __restrict__ s2v,
    float2* __restrict__ mz, float* __restrict__ att,
    short* __restrict__ qb8) {
  const int wave = threadIdx.x >> 6;
  const int lane = threadIdx.x & 63;
  const int row = blockIdx.x * 4 + wave;
  const float* arow = adj + (size_t)row * NN;
  int* outp = nbr + (size_t)row * MAXD;
  int count = 0;
  int dflag = 0;
  int b[7];
  const unsigned long long below = (1ull << lane) - 1ull;
  for (int c0 = 0; c0 < NN; c0 += 256) {
    if (c0 > 0 && (c0 & 1023) == 0) b[(c0 >> 10) - 1] = count;
    const int c = c0 + lane * 4;
    const f32x4 v = __builtin_nontemporal_load(
        reinterpret_cast<const f32x4*>(arow + c));
    const unsigned long long m0 = __ballot(v[0] > 0.0f);
    const unsigned long long m1 = __ballot(v[1] > 0.0f);
    const unsigned long long m2 = __ballot(v[2] > 0.0f);
    const unsigned long long m3 = __ballot(v[3] > 0.0f);
    int pos = count + (int)(__popcll(m0 & below) + __popcll(m1 & below) +
                            __popcll(m2 & below) + __popcll(m3 & below));
    if (v[0] > 0.0f) { if (pos < MAXD) outp[pos] = c + 0; ++pos; if (c + 0 == row) dflag = 1; }
    if (v[1] > 0.0f) { if (pos < MAXD) outp[pos] = c + 1; ++pos; if (c + 1 == row) dflag = 1; }
    if (v[2] > 0.0f) { if (pos < MAXD) outp[pos] = c + 2; ++pos; if (c + 2 == row) dflag = 1; }
    if (v[3] > 0.0f) { if (pos < MAXD) outp[pos] = c + 3; ++pos; if (c + 3 == row) dflag = 1; }
    count += (int)(__popcll(m0) + __popcll(m1) + __popcll(m2) + __popcll(m3));
  }
  const int anyd = __any(dflag) ? 1 : 0;
  const int d = count < MAXD ? count : MAXD;
  if (lane == 0) {
    deg[row] = d;
    s2v[row] = count - anyd;
    short* q = qb8 + (size_t)row * 8;
#pragma unroll
    for (int w = 0; w < 7; ++w) {
      const int bw = b[w] < d ? b[w] : d;
      q[w] = (short)bw;
    }
    q[7] = (short)d;
  }
  const size_t rowbase = (size_t)row * MAXD;
  const int* cols = outp;
  const float w1 = Wh1[row];
  int c0i = 0x7fffffff, c1i = 0x7fffffff, c2i = 0x7fffffff;
  float e0 = -1e30f, e1 = -1e30f, e2 = -1e30f;
  const bool a0 = lane < d, a1 = lane + 64 < d, a2 = lane + 128 < d;
  if (a0) { c0i = cols[lane];       float x = w1 + Wh2[c0i]; e0 = x > 0.0f ? x : LRALPHA * x; }
  if (a1) { c1i = cols[lane + 64];  float x = w1 + Wh2[c1i]; e1 = x > 0.0f ? x : LRALPHA * x; }
  if (a2) { c2i = cols[lane + 128]; float x = w1 + Wh2[c2i]; e2 = x > 0.0f ? x : LRALPHA * x; }
  float mx = fmaxf(e0, fmaxf(e1, e2));
  for (int o = 32; o > 0; o >>= 1) mx = fmaxf(mx, __shfl_xor(mx, o));
  const float x0 = a0 ? expf(e0 - mx) : 0.0f;
  const float x1 = a1 ? expf(e1 - mx) : 0.0f;
  const float x2 = a2 ? expf(e2 - mx) : 0.0f;
  float sum = x0 + x1 + x2;
  for (int o = 32; o > 0; o >>= 1) sum += __shfl_xor(sum, o);
  const float Z = (d > 0) ? sum : 1.0f;
  const float invZ = 1.0f / Z;
  if (a0) att[rowbase + lane] = x0 * invZ;
  if (a1) att[rowbase + lane + 64] = x1 * invZ;
  if (a2) att[rowbase + lane + 128] = x2 * invZ;
  if (lane == 0) mz[row] = make_float2(mx, invZ);
}

// ---------------------------------------------------------------------------
// Kernel D2: packed transpose-edge values + h_prime (bf16 Whb gather).
// ---------------------------------------------------------------------------
__global__ void __launch_bounds__(256) k_att(
    const int* __restrict__ nbr, const int* __restrict__ deg,
    const float* __restrict__ Wh1, const float* __restrict__ Wh2,
    const float2* __restrict__ mz, const float* __restrict__ att,
    const float* __restrict__ Wh, const unsigned short* __restrict__ Whb,
    int2* __restrict__ edgesT, float* __restrict__ out0) {
  const int wave = threadIdx.x >> 6;
  const int lane = threadIdx.x & 63;
  const int row = blockIdx.x * 4 + wave;
  const int d = deg[row];
  const size_t rowbase = (size_t)row * MAXD;
  const int* cols = nbr + rowbase;
  const float w2r = Wh2[row];
  for (int t = lane; t < d; t += 64) {
    const int j = cols[t];
    float e2 = Wh1[j] + w2r;
    e2 = e2 > 0.0f ? e2 : LRALPHA * e2;
    const float2 m = mz[j];
    const float v = expf(e2 - m.x) * m.y;
    edgesT[rowbase + t] = make_int2(j, __float_as_int(v));
  }
  {
    const float* arow = att + rowbase;
    f32x4 p0 = {0, 0, 0, 0}, p1 = {0, 0, 0, 0};
    f32x4 p2 = {0, 0, 0, 0}, p3 = {0, 0, 0, 0};
    int t = 0;
    if (Whb) {
      for (; t + 3 < d; t += 4) {
        const int j0 = cols[t], j1 = cols[t + 1], j2 = cols[t + 2], j3 = cols[t + 3];
        const float w0 = arow[t], w1 = arow[t + 1], w2 = arow[t + 2], w3 = arow[t + 3];
        const ushort4 b0 = *reinterpret_cast<const ushort4*>(Whb + (size_t)j0 * KFOUT + lane * 4);
        const ushort4 b1 = *reinterpret_cast<const ushort4*>(Whb + (size_t)j1 * KFOUT + lane * 4);
        const ushort4 b2 = *reinterpret_cast<const ushort4*>(Whb + (size_t)j2 * KFOUT + lane * 4);
        const ushort4 b3 = *reinterpret_cast<const ushort4*>(Whb + (size_t)j3 * KFOUT + lane * 4);
        const f32x4 a0 = {bf16_to_f32(b0.x), bf16_to_f32(b0.y), bf16_to_f32(b0.z), bf16_to_f32(b0.w)};
        const f32x4 a1 = {bf16_to_f32(b1.x), bf16_to_f32(b1.y), bf16_to_f32(b1.z), bf16_to_f32(b1.w)};
        const f32x4 a2 = {bf16_to_f32(b2.x), bf16_to_f32(b2.y), bf16_to_f32(b2.z), bf16_to_f32(b2.w)};
        const f32x4 a3 = {bf16_to_f32(b3.x), bf16_to_f32(b3.y), bf16_to_f32(b3.z), bf16_to_f32(b3.w)};
        p0 += w0 * a0;
        p1 += w1 * a1;
        p2 += w2 * a2;
        p3 += w3 * a3;
      }
      for (; t < d; ++t) {
        const int j = cols[t];
        const float w = arow[t];
        const ushort4 b = *reinterpret_cast<const ushort4*>(Whb + (size_t)j * KFOUT + lane * 4);
        const f32x4 av = {bf16_to_f32(b.x), bf16_to_f32(b.y), bf16_to_f32(b.z), bf16_to_f32(b.w)};
        p0 += w * av;
      }
    } else {
      for (; t + 3 < d; t += 4) {
        const int j0 = cols[t], j1 = cols[t + 1], j2 = cols[t + 2], j3 = cols[t + 3];
        const float w0 = arow[t], w1 = arow[t + 1], w2 = arow[t + 2], w3 = arow[t + 3];
        const f32x4 a0 = *reinterpret_cast<const f32x4*>(Wh + (size_t)j0 * KFOUT + lane * 4);
        const f32x4 a1 = *reinterpret_cast<const f32x4*>(Wh + (size_t)j1 * KFOUT + lane * 4);
        const f32x4 a2 = *reinterpret_cast<const f32x4*>(Wh + (size_t)j2 * KFOUT + lane * 4);
        const f32x4 a3 = *reinterpret_cast<const f32x4*>(Wh + (size_t)j3 * KFOUT + lane * 4);
        p0 += w0 * a0;
        p1 += w1 * a1;
        p2 += w2 * a2;
        p3 += w3 * a3;
      }
      for (; t < d; ++t) {
        const int j = cols[t];
        const float w = arow[t];
        p0 += w * *reinterpret_cast<const f32x4*>(Wh + (size_t)j * KFOUT + lane * 4);
      }
    }
    const f32x4 r = (p0 + p1) + (p2 + p3);
    f32x4 o;
    o[0] = r[0] > 0.0f ? r[0] : expm1f(r[0]);
    o[1] = r[1] > 0.0f ? r[1] : expm1f(r[1]);
    o[2] = r[2] > 0.0f ? r[2] : expm1f(r[2]);
    o[3] = r[3] > 0.0f ? r[3] : expm1f(r[3]);
    __builtin_nontemporal_store(
        o, reinterpret_cast<f32x4*>(&out0[(size_t)row * KFOUT + lane * 4]));
  }
}

// ---------------------------------------------------------------------------
// Kernel E: BARRIER-MINIMIZED select (16 -> 6 block barriers).
// - hist/shNc init folded into staging (before B1).
// - diag zero by owner wave in its octant phase (no barrier).
// - passes 1-3 run on WAVE 0 ONLY over the <=512 compact candidates
//   (8 register values/lane, wave-private LDS hist, wave-synchronous
//   ordering -> zero block barriers). Dense barriered fallback if nc>512.
// Scatter unchanged (R6 octant group expansion, replay-deterministic).
// ---------------------------------------------------------------------------
__global__ void __launch_bounds__(512) k_twostep(
    const int* __restrict__ nbr, const int* __restrict__ deg,
    const int* __restrict__ s2v, const float* __restrict__ att,
    const int2* __restrict__ edgesT, const short* __restrict__ qb8,
    float* __restrict__ out1) {
  __shared__ float comb[NN];                 // 32768 B
  __shared__ float wvals[MAXD];              //   768 B
  __shared__ unsigned short kcols[MAXD];     //   384 B
  __shared__ short sqb[MAXD][8];             //  3072 B
  __shared__ unsigned int hist[256];         //  1024 B
  __shared__ unsigned int scomp[512];        //  2048 B
  __shared__ unsigned int shPrefix;
  __shared__ int shRemaining;
  __shared__ int shNc;
  const int tid = threadIdx.x;
  const int wave = tid >> 6;
  const int lane = tid & 63;
  const int row = blockIdx.x;
  const f32x4 z4 = {0.0f, 0.0f, 0.0f, 0.0f};
  for (int j = tid * 4; j < NN; j += 2048)
    *reinterpret_cast<f32x4*>(&comb[j]) = z4;
  const int d = deg[row];
  const int* cols = nbr + (size_t)row * MAXD;
  const float* arow = att + (size_t)row * MAXD;
  for (int t = tid; t < d; t += 512) {
    const int c = cols[t];
    kcols[t] = (unsigned short)c;
    wvals[t] = arow[t];
    *reinterpret_cast<int4*>(&sqb[t][0]) =
        *reinterpret_cast<const int4*>(&qb8[(size_t)c * 8]);
  }
  if (tid < 256) hist[tid] = 0u;  // pre-zeroed before B1
  if (tid == 0) shNc = 0;
  __syncthreads();  // B1
  // --- scatter (R6 form) + own-att + diag zero, all octant-exclusive
  {
    const int grp = lane >> 3;
    const int sub = lane & 7;
    for (int t0 = 0; t0 < d; t0 += 8) {
      const int t = t0 + grp;
      if (t < d) {
        const int qs = wave ? (int)sqb[t][wave - 1] : 0;
        const int qe = (int)sqb[t][wave];
        const float w = wvals[t];
        const int2* ek = edgesT + (size_t)kcols[t] * MAXD;
        for (int off = qs + sub; off < qe; off += 8) {
          const int2 e = ek[off];
          atomicAdd(&comb[e.x], w * __int_as_float(e.y));
        }
      }
    }
    const short* qr = qb8 + (size_t)row * 8;
    const int qlo = wave ? (int)qr[wave - 1] : 0;
    const int qhi = (int)qr[wave];
    for (int t = qlo + lane; t < qhi; t += 64) comb[(int)kcols[t]] += wvals[t];
    if (lane == 0 && wave == (row >> 10)) comb[row] = 0.0f;  // owner wave
  }
  __syncthreads();  // B2
  const int kk = s2v[row];
  const size_t obase = (size_t)row * NN;
  if (kk <= 0) {
    for (int j = tid * 4; j < NN; j += 2048)
      __builtin_nontemporal_store(z4, reinterpret_cast<f32x4*>(&out1[obase + j]));
    return;
  }
  // --- pass 0: dense 8-bit hist (hist pre-zeroed)
  for (int j = tid * 4; j < NN; j += 2048) {
    const f32x4 cv = *reinterpret_cast<const f32x4*>(&comb[j]);
#pragma unroll
    for (int q = 0; q < 4; ++q) {
      const unsigned int u = __float_as_uint(cv[q]);
      if (u != 0u) atomicAdd(&hist[u >> 24], 1u);
    }
  }
  __syncthreads();  // B3
  if (tid < 64) {
    const int bHi = 255 - 4 * lane;
    const unsigned int c0 = hist[bHi];
    const unsigned int c1 = hist[bHi - 1];
    const unsigned int c2 = hist[bHi - 2];
    const unsigned int c3 = hist[bHi - 3];
    const unsigned int gs = c0 + c1 + c2 + c3;
    unsigned int run2 = gs;
    for (int o = 1; o < 64; o <<= 1) {
      const unsigned int tt = __shfl_up(run2, o);
      if (lane >= o) run2 += tt;
    }
    const unsigned int pre = run2 - gs;
    const unsigned int rem = (unsigned int)kk;
    if (pre < rem && pre + gs >= rem) {
      unsigned int above;
      int digit;
      if (pre + c0 >= rem) { digit = bHi; above = pre; }
      else if (pre + c0 + c1 >= rem) { digit = bHi - 1; above = pre + c0; }
      else if (pre + c0 + c1 + c2 >= rem) { digit = bHi - 2; above = pre + c0 + c1; }
      else { digit = bHi - 3; above = pre + c0 + c1 + c2; }
      shPrefix = (unsigned)digit << 24;
      shRemaining = kk - (int)above;
    }
  }
  __syncthreads();  // B4
  const unsigned int prefix0 = shPrefix;
  const int remaining0 = shRemaining;
  const unsigned int digit0 = prefix0 >> 24;
  // --- compact the chosen bin's candidates (order-independent multiset)
  for (int j = tid * 4; j < NN; j += 2048) {
    const f32x4 cv = *reinterpret_cast<const f32x4*>(&comb[j]);
#pragma unroll
    for (int q = 0; q < 4; ++q) {
      const unsigned int u = __float_as_uint(cv[q]);
      if (u != 0u && (u >> 24) == digit0) {
        const int idx = atomicAdd(&shNc, 1);
        if (idx < 512) scomp[idx] = u;
      }
    }
  }
  __syncthreads();  // B5
  const int nc = shNc;
  if (nc <= 512) {
    // --- wave-0-only passes 1-3 on the compact array: no block barriers
    if (wave == 0) {
      unsigned v0 = 0, v1 = 0, v2 = 0, v3 = 0, v4 = 0, v5 = 0, v6 = 0, v7 = 0;
      bool m0_ = false, m1_ = false, m2_ = false, m3_ = false;
      bool m4_ = false, m5_ = false, m6_ = false, m7_ = false;
#define LDV(I) { const int ix = lane + 64 * I; \
                 if (ix < nc) { v##I = scomp[ix]; m##I##_ = true; } }
      LDV(0) LDV(1) LDV(2) LDV(3) LDV(4) LDV(5) LDV(6) LDV(7)
#undef LDV
      unsigned prefix = prefix0;
      int remaining = remaining0;
#pragma unroll
      for (int pass = 1; pass < 4; ++pass) {
        const int shift = 24 - 8 * pass;
        const unsigned pmask = 0xFFFFFFFFu << (shift + 8);
        for (int b2 = lane; b2 < 256; b2 += 64) hist[b2] = 0u;
#define HADD(I) if (m##I##_ && (v##I & pmask) == prefix) \
                  atomicAdd(&hist[(v##I >> shift) & 255u], 1u);
        HADD(0) HADD(1) HADD(2) HADD(3) HADD(4) HADD(5) HADD(6) HADD(7)
#undef HADD
        const int bHi = 255 - 4 * lane;
        const unsigned c0 = hist[bHi];
        const unsigned c1 = hist[bHi - 1];
        const unsigned c2 = hist[bHi - 2];
        const unsigned c3 = hist[bHi - 3];
        const unsigned gs = c0 + c1 + c2 + c3;
        unsigned run2 = gs;
        for (int o = 1; o < 64; o <<= 1) {
          const unsigned tt = __shfl_up(run2, o);
          if (lane >= o) run2 += tt;
        }
        const unsigned pre = run2 - gs;
        const unsigned rem = (unsigned)remaining;
        // find hit lane, broadcast (newprefix, newrem) via shfl
        unsigned npref = 0u;
        int nrem = 0;
        const bool hit = (pre < rem && pre + gs >= rem);
        if (hit) {
          unsigned above;
          int digit;
          if (pre + c0 >= rem) { digit = bHi; above = pre; }
          else if (pre + c0 + c1 >= rem) { digit = bHi - 1; above = pre + c0; }
          else if (pre + c0 + c1 + c2 >= rem) { digit = bHi - 2; above = pre + c0 + c1; }
          else { digit = bHi - 3; above = pre + c0 + c1 + c2; }
          npref = prefix | ((unsigned)digit << shift);
          nrem = remaining - (int)above;
        }
        const unsigned long long hm = __ballot(hit);
        const int hl = (int)__ffsll((long long)hm) - 1;
        prefix = __shfl(npref, hl);
        remaining = __shfl(nrem, hl);
      }
      if (lane == 0) shPrefix = prefix;
    }
  } else {
    // --- rare dense fallback (barriered)
    unsigned prefix = prefix0;
    int remaining = remaining0;
    for (int pass = 1; pass < 4; ++pass) {
      const int shift = 24 - 8 * pass;
      const unsigned pmask = 0xFFFFFFFFu << (shift + 8);
      if (tid < 256) hist[tid] = 0u;
      __syncthreads();
      for (int j = tid * 4; j < NN; j += 2048) {
        const f32x4 cv = *reinterpret_cast<const f32x4*>(&comb[j]);
#pragma unroll
        for (int q = 0; q < 4; ++q) {
          const unsigned int u = __float_as_uint(cv[q]);
          if (u != 0u && (u & pmask) == prefix)
            atomicAdd(&hist[(u >> shift) & 255u], 1u);
        }
      }
      __syncthreads();
      if (tid < 64) {
        const int bHi = 255 - 4 * lane;
        const unsigned c0 = hist[bHi];
        const unsigned c1 = hist[bHi - 1];
        const unsigned c2 = hist[bHi - 2];
        const unsigned c3 = hist[bHi - 3];
        const unsigned gs = c0 + c1 + c2 + c3;
        unsigned run2 = gs;
        for (int o = 1; o < 64; o <<= 1) {
          const unsigned tt = __shfl_up(run2, o);
          if (lane >= o) run2 += tt;
        }
        const unsigned pre = run2 - gs;
        const unsigned rem = (unsigned)remaining;
        if (pre < rem && pre + gs >= rem) {
          unsigned above;
          int digit;
          if (pre + c0 >= rem) { digit = bHi; above = pre; }
          else if (pre + c0 + c1 >= rem) { digit = bHi - 1; above = pre + c0; }
          else if (pre + c0 + c1 + c2 >= rem) { digit = bHi - 2; above = pre + c0 + c1; }
          else { digit = bHi - 3; above = pre + c0 + c1 + c2; }
          shPrefix = prefix | ((unsigned)digit << shift);
          shRemaining = remaining - (int)above;
        }
      }
      __syncthreads();
      prefix = shPrefix;
      remaining = shRemaining;
      __syncthreads();
    }
  }
  __syncthreads();  // B6
  const float thr = __uint_as_float(shPrefix);  // exact kk-th largest value
  for (int j = tid * 4; j < NN; j += 2048) {
    const f32x4 cv = *reinterpret_cast<const f32x4*>(&comb[j]);
    f32x4 ov;
    ov[0] = (cv[0] >= thr && cv[0] > 0.0f) ? 1.0f : 0.0f;
    ov[1] = (cv[1] >= thr && cv[1] > 0.0f) ? 1.0f : 0.0f;
    ov[2] = (cv[2] >= thr && cv[2] > 0.0f) ? 1.0f : 0.0f;
    ov[3] = (cv[3] >= thr && cv[3] > 0.0f) ? 1.0f : 0.0f;
    __builtin_nontemporal_store(ov, reinterpret_cast<f32x4*>(&out1[obase + j]));
  }
}

extern "C" void kernel_launch(void* const* d_in, const int* in_sizes, int n_in,
                              void* d_out, int out_size, void* d_ws, size_t ws_size,
                              hipStream_t stream) {
  const float* h = (const float*)d_in[0];
  const float* adj = (const float*)d_in[1];
  const float* W = (const float*)d_in[2];
  const float* a = (const float*)d_in[3];

  float* out0 = (float*)d_out;                  // [8192, 256] elu(h_prime)
  float* out1 = out0 + (size_t)NN * KFOUT;      // [8192, 8192] adj_resize

  // workspace layout (~34 MB base, +4 MB Whb if room)
  float* Wh = (float*)d_ws;                        // 8192*256
  float* Wh1 = Wh + (size_t)NN * KFOUT;            // 8192
  float* Wh2 = Wh1 + NN;                           // 8192
  float* mrow = Wh2 + NN;                          // 8192 (unused legacy slot)
  float* Zrow = mrow + NN;                         // 8192 (unused legacy slot)
  float* att = Zrow + NN;                          // 8192*MAXD
  float* edgesF = att + (size_t)NN * MAXD;         // 8192*MAXD int2
  int2* edgesT = (int2*)edgesF;
  int* nbr = (int*)(edgesF + (size_t)NN * MAXD * 2);  // 8192*MAXD
  int* deg = nbr + (size_t)NN * MAXD;              // 8192
  int* s2v = deg + NN;                             // 8192
  short* qb8 = (short*)(s2v + NN);                 // 8192*8 shorts (128 KB)
  float2* mz = (float2*)(qb8 + (size_t)NN * 8);    // 8192 float2 (64 KB)
  unsigned short* Whb = (unsigned short*)(mz + NN);  // 8192*256 u16 (4 MB)
  const size_t need =
      (size_t)((char*)(Whb + (size_t)NN * KFOUT) - (char*)d_ws);
  const bool useB = ws_size >= need;
  unsigned short* WhbArg = useB ? Whb : nullptr;

  dim3 ggrid(KFOUT / 64, NN / 64);
  k_gemm<<<ggrid, 256, 0, stream>>>(h, W, Wh, WhbArg);
  k_rowdots<<<NN / 4, 256, 0, stream>>>(Wh, a, Wh1, Wh2);
  k_csr_stats<<<NN / 4, 256, 0, stream>>>(adj, Wh1, Wh2, nbr, deg, s2v, mz,
                                          att, qb8);
  k_att<<<NN / 4, 256, 0, stream>>>(nbr, deg, Wh1, Wh2, mz, att, Wh, WhbArg,
                                    edgesT, out0);
  k_twostep<<<NN, 512, 0, stream>>>(nbr, deg, s2v, att, edgesT, qb8, out1);
}